// Round 8
// baseline (318.436 us; speedup 1.0000x reference)
//
#include <hip/hip_runtime.h>
#include <hip/hip_bf16.h>
#include <cstdint>
#include <cstddef>

#define B_ 2
#define S_ 2048
#define D_ 2048
#define H_ 32
#define KVH_ 8
#define HD_ 64
#define PROJN 3072   // Q_OUT(2048) + 2*KV_OUT(512)

typedef unsigned short u16;
typedef unsigned int u32;
typedef __attribute__((ext_vector_type(8))) short short8;
typedef __attribute__((ext_vector_type(4))) short short4v;
typedef __attribute__((ext_vector_type(4))) float f32x4;

__device__ __forceinline__ u16 f2bf(float f) {
  __hip_bfloat16 h = __float2bfloat16(f);
  return *reinterpret_cast<u16*>(&h);
}

#define GLDS16(g, l)                                                           \
  __builtin_amdgcn_global_load_lds(                                            \
      (const __attribute__((address_space(1))) void*)(g),                      \
      (__attribute__((address_space(3))) void*)(l), 16, 0, 0)

// ---------------- pack f32 -> bf16 ----------------
__global__ __launch_bounds__(256) void pack_bf16(const float* __restrict__ in,
                                                 u16* __restrict__ out, int n) {
  int i = (blockIdx.x * 256 + threadIdx.x) * 8;
  if (i >= n) return;
  const float4* p = reinterpret_cast<const float4*>(in + i);
  float4 a = p[0], b = p[1];
  union { short8 v; u16 u[8]; } r;
  r.u[0] = f2bf(a.x); r.u[1] = f2bf(a.y); r.u[2] = f2bf(a.z); r.u[3] = f2bf(a.w);
  r.u[4] = f2bf(b.x); r.u[5] = f2bf(b.y); r.u[6] = f2bf(b.z); r.u[7] = f2bf(b.w);
  *reinterpret_cast<short8*>(out + i) = r.v;
}

// ---------------- rope cos/sin table ----------------
__global__ __launch_bounds__(256) void rope_table(float* __restrict__ tc,
                                                  float* __restrict__ ts) {
  int i = blockIdx.x * 256 + threadIdx.x;  // S_*32
  int s = i >> 5, j = i & 31;
  float e = (float)(2 * j) / 64.0f;
  float inv_freq = 1.0f / powf(10000.0f, e);
  float ang = (float)s * inv_freq;
  tc[i] = cosf(ang);
  ts[i] = sinf(ang);
}

// ---------------- bf16 GEMM: C[M,N] = A[M,K] * Bw[N,K]^T ----------------
__global__ __launch_bounds__(256) void gemm_bt(const u16* __restrict__ A,
                                               const u16* __restrict__ Bw,
                                               float* __restrict__ C, int M,
                                               int N, int K) {
  __shared__ u16 As[128 * 64];
  __shared__ u16 Bs[128 * 64];
  const int tid = threadIdx.x;
  const int lane = tid & 63;
  const int wave = tid >> 6;
  const int ntile = N >> 7;
  const int m0 = (blockIdx.x / ntile) << 7;
  const int n0 = (blockIdx.x % ntile) << 7;
  const int wr = (wave >> 1) << 6;
  const int wc = (wave & 1) << 6;
  const int arow = lane & 15;
  const int kgrp = lane >> 4;

  const f32x4 zero4 = {0.f, 0.f, 0.f, 0.f};
  f32x4 acc[4][4];
#pragma unroll
  for (int m = 0; m < 4; m++)
#pragma unroll
    for (int n = 0; n < 4; n++) acc[m][n] = zero4;

  int srow[4], sslot[4];
#pragma unroll
  for (int i = 0; i < 4; i++) {
    int c = i * 256 + tid;
    srow[i] = c >> 3;
    sslot[i] = (c & 7) ^ (srow[i] & 7);  // inverse-swizzled source slot
  }

  auto stage = [&](int kt) {
    const int k0 = kt << 6;
#pragma unroll
    for (int i = 0; i < 4; i++) {
      const u16* ga = A + (size_t)(m0 + srow[i]) * K + k0 + sslot[i] * 8;
      GLDS16(ga, As + (i * 256 + tid) * 8);
    }
#pragma unroll
    for (int i = 0; i < 4; i++) {
      const u16* gb = Bw + (size_t)(n0 + srow[i]) * K + k0 + sslot[i] * 8;
      GLDS16(gb, Bs + (i * 256 + tid) * 8);
    }
  };

  const int KT = K >> 6;
  stage(0);
  for (int kt = 0;; kt++) {
    __syncthreads();  // staging drained (compiler emits vmcnt(0) before barrier)
#pragma unroll
    for (int ks = 0; ks < 2; ks++) {
      const int sd = ks * 4 + kgrp;
      short8 a[4], b[4];
#pragma unroll
      for (int m = 0; m < 4; m++) {
        int r = wr + m * 16 + arow;
        a[m] = *reinterpret_cast<const short8*>(As + r * 64 + ((sd ^ (r & 7)) << 3));
      }
#pragma unroll
      for (int n = 0; n < 4; n++) {
        int r = wc + n * 16 + arow;
        b[n] = *reinterpret_cast<const short8*>(Bs + r * 64 + ((sd ^ (r & 7)) << 3));
      }
#pragma unroll
      for (int m = 0; m < 4; m++)
#pragma unroll
        for (int n = 0; n < 4; n++)
          acc[m][n] = __builtin_amdgcn_mfma_f32_16x16x32_bf16(a[m], b[n], acc[m][n], 0, 0, 0);
    }
    if (kt + 1 == KT) break;
    __syncthreads();
    stage(kt + 1);
  }

  const int crow = kgrp * 4;
#pragma unroll
  for (int m = 0; m < 4; m++) {
#pragma unroll
    for (int n = 0; n < 4; n++) {
      float* cp = C + (size_t)(m0 + wr + m * 16 + crow) * N + n0 + wc + n * 16 + arow;
#pragma unroll
      for (int r = 0; r < 4; r++) cp[(size_t)r * N] = acc[m][n][r];
    }
  }
}

// ---------------- RoPE + RMSNorm for Q and K ----------------
// one wave per (b, s, head'), head' in [0,40): 0..31 Q heads, 32..39 K heads
__global__ __launch_bounds__(256) void rope_norm(
    const float* __restrict__ proj, const float* __restrict__ tc,
    const float* __restrict__ ts, const float* __restrict__ gain,
    u16* __restrict__ Qn, u16* __restrict__ Kn) {
  int wid = (blockIdx.x * 256 + threadIdx.x) >> 6;  // B_*S_*40 waves
  int lane = threadIdx.x & 63;
  int hh = wid % 40;
  int bs = wid / 40;  // b*S_ + s
  int s = bs & (S_ - 1);
  int b = bs >> 11;
  int off = hh < 32 ? hh * 64 + lane : 2048 + (hh - 32) * 64 + lane;
  float val = proj[(size_t)bs * PROJN + off];
  int j = lane & 31;
  float c = tc[s * 32 + j], sn = ts[s * 32 + j];
  float partner = __shfl_xor(val, 32);
  float out = lane < 32 ? val * c - partner * sn : val * c + partner * sn;
  float ss = out * out;
#pragma unroll
  for (int m = 32; m >= 1; m >>= 1) ss += __shfl_xor(ss, m);
  float inv = rsqrtf(ss * (1.0f / 64.0f) + 1e-6f);
  float g = hh < 32 ? gain[0] : 1.0f;
  u16 ub = f2bf(out * inv * g);
  if (hh < 32)
    Qn[(((size_t)(b * H_ + hh)) * S_ + s) * HD_ + lane] = ub;
  else
    Kn[(((size_t)(b * KVH_ + (hh - 32))) * S_ + s) * HD_ + lane] = ub;
}

// ---------------- V: transpose to (B,KVH,HD,S) bf16 + V_flat f32 output ----------------
__global__ __launch_bounds__(256) void vtrans(const float* __restrict__ proj,
                                              u16* __restrict__ Vt,
                                              float* __restrict__ Vout) {
  __shared__ float tile[64][65];
  const int bid = blockIdx.x;  // B_*KVH_*(S_/64)
  const int st = bid & 31;
  const int s0 = st << 6;
  const int kvh = (bid >> 5) & 7;
  const int b = bid >> 8;
  const int t = threadIdx.x;
  const int sr = t >> 2;
  const int d0 = (t & 3) << 4;
  const float* src = proj + ((size_t)(b * S_ + s0 + sr)) * PROJN + 2560 + kvh * 64 + d0;
  float v[16];
#pragma unroll
  for (int i = 0; i < 16; i += 4) {
    float4 x = *reinterpret_cast<const float4*>(src + i);
    v[i] = x.x; v[i + 1] = x.y; v[i + 2] = x.z; v[i + 3] = x.w;
  }
  // V_flat output: rows h*B+b, 4 repeated heads (scale rsqrt(1+1e-8) == 1.0f exactly)
#pragma unroll
  for (int hh = 0; hh < 4; hh++) {
    int hq = kvh * 4 + hh;
    float* dst = Vout + (((size_t)(hq * B_ + b)) * S_ + s0 + sr) * HD_ + d0;
#pragma unroll
    for (int i = 0; i < 16; i += 4)
      *reinterpret_cast<float4*>(dst + i) = make_float4(v[i], v[i + 1], v[i + 2], v[i + 3]);
  }
#pragma unroll
  for (int i = 0; i < 16; i++) tile[sr][d0 + i] = v[i];
  __syncthreads();
  const int d = t >> 2;
  const int sc = (t & 3) << 4;
  union { short8 v8; u16 u[8]; } o0, o1;
#pragma unroll
  for (int i = 0; i < 8; i++) o0.u[i] = f2bf(tile[sc + i][d]);
#pragma unroll
  for (int i = 0; i < 8; i++) o1.u[i] = f2bf(tile[sc + 8 + i][d]);
  u16* dst = Vt + (((size_t)(b * KVH_ + kvh)) * HD_ + d) * S_ + s0 + sc;
  *reinterpret_cast<short8*>(dst) = o0.v8;
  *reinterpret_cast<short8*>(dst + 8) = o1.v8;
}

// ---------------- flash attention (causal, GQA) ----------------
// Block = (b, kvh, q-tile PAIR {u, 63-u}). FIXED-C softmax (see R6 comment).
// R8: (a) Ps shrunk to [wave][2] (wave-private, DS in-order => read pa inside
// the p-loop before the buffer is reused) -> LDS 48KB -> 3 blocks/CU.
// (b) denominator via ones-row MFMA: A-frag = 1.0 on lanes ql==0 => row 0 of
// mfma(ones, P) = sum_k P[k][q]; replaces 64 VALU adds/iter with 8 MFMA.
__global__ __launch_bounds__(256, 3) void attn_fwd(const u16* __restrict__ Qn,
                                                   const u16* __restrict__ Kn,
                                                   const u16* __restrict__ Vt,
                                                   u16* __restrict__ Aout) {
  __shared__ u16 Ks[2][64 * 64];
  __shared__ u16 Vs[2][64 * 64];
  __shared__ u16 Ps[4][2][1024];  // [wave][half-frag][16 q-rows x 64 kv]
  const int bid = blockIdx.x;     // B_*KVH_*32
  const int u = bid & 31;
  const int kvh = (bid >> 5) & 7;
  const int b = bid >> 8;
  const int q0A = u << 5;
  const int q0B = (63 - u) << 5;
  const int JT_A = (u >> 1) + 1;
  const int JT_B = 32 - (u >> 1);
  const int tid = threadIdx.x;
  const int lane = tid & 63;
  const int wave = tid >> 6;
  const int h = kvh * 4 + wave;  // this wave's Q head
  const int ql = lane & 15;
  const int g = lane >> 4;
  const float SCL2E = 0.125f * 1.44269504088896340736f;

  // Q frags: ff=0,1 -> tile A rows q0A+16*ff+ql; ff=2,3 -> tile B
  short8 qa[4][2];
  int rowq[4];
#pragma unroll
  for (int ff = 0; ff < 4; ff++) {
    const int q0 = (ff < 2) ? q0A : q0B;
    rowq[ff] = q0 + 16 * (ff & 1) + ql;
    const u16* qb = Qn + (((size_t)(b * H_ + h)) * S_ + rowq[ff]) * HD_;
    qa[ff][0] = *reinterpret_cast<const short8*>(qb + g * 8);
    qa[ff][1] = *reinterpret_cast<const short8*>(qb + 32 + g * 8);
  }

  // ones A-fragment: A[row][k] = (row==0) ? 1.0 : 0 -> lane ql==0 holds 1.0bf16
  short8 ones_af;
  {
    const short ov = (ql == 0) ? (short)0x3F80 : (short)0;
#pragma unroll
    for (int e = 0; e < 8; e++) ones_af[e] = ov;
  }

  const f32x4 zero4 = {0.f, 0.f, 0.f, 0.f};
  f32x4 oacc[4][4];  // [dn][ff]
#pragma unroll
  for (int dn = 0; dn < 4; dn++)
#pragma unroll
    for (int ff = 0; ff < 4; ff++) oacc[dn][ff] = zero4;
  f32x4 sacc[4];  // denominator accumulators (row 0 = sum)
#pragma unroll
  for (int ff = 0; ff < 4; ff++) sacc[ff] = zero4;

  const u16* kg = Kn + ((size_t)(b * KVH_ + kvh)) * S_ * HD_;
  const u16* vg = Vt + ((size_t)(b * KVH_ + kvh)) * HD_ * S_;

  const int c0 = tid, c1 = 256 + tid;
  const int r0 = c0 >> 3, sl0 = (c0 & 7) ^ (r0 & 7);
  const int r1 = c1 >> 3, sl1 = (c1 & 7) ^ (r1 & 7);
  const int xsw2 = (ql & 7) << 2;

  auto stage = [&](int jt, int buf) {
    const int j0 = jt << 6;
    GLDS16(kg + (size_t)(j0 + r0) * HD_ + sl0 * 8, Ks[buf] + c0 * 8);
    GLDS16(kg + (size_t)(j0 + r1) * HD_ + sl1 * 8, Ks[buf] + c1 * 8);
    GLDS16(vg + (size_t)r0 * S_ + j0 + sl0 * 8, Vs[buf] + c0 * 8);
    GLDS16(vg + (size_t)r1 * S_ + j0 + sl1 * 8, Vs[buf] + c1 * 8);
  };

  stage(0, 0);
  __syncthreads();  // drain prologue stage
  int cur = 0;
  for (int jt = 0; jt < JT_B; jt++) {
    if (jt + 1 < JT_B) stage(jt + 1, cur ^ 1);  // issue next tile early
    const int j0 = jt << 6;
    const u16* ksb = Ks[cur];
    const u16* vsb = Vs[cur];
    const bool actA = (jt < JT_A);

    short8 pa[4][2];
    // per q-tile pair: S^T = K·Q^T, then p = exp2(fma(s,SCL2E,-12)), pack->LDS,
    // read back B-frags (wave-private buffer, DS in-order)
#pragma unroll
    for (int p = 0; p < 2; p++) {
      if (p == 0 && !actA) continue;
      f32x4 sc[4][2];
#pragma unroll
      for (int n = 0; n < 4; n++)
#pragma unroll
        for (int f = 0; f < 2; f++) sc[n][f] = zero4;
      __builtin_amdgcn_s_setprio(1);
#pragma unroll
      for (int ks = 0; ks < 2; ks++) {
        const int sd = ks * 4 + g;
#pragma unroll
        for (int n = 0; n < 4; n++) {
          const int r = n * 16 + ql;
          short8 kf = *reinterpret_cast<const short8*>(ksb + r * 64 + ((sd ^ (r & 7)) << 3));
          sc[n][0] = __builtin_amdgcn_mfma_f32_16x16x32_bf16(kf, qa[2 * p][ks], sc[n][0], 0, 0, 0);
          sc[n][1] = __builtin_amdgcn_mfma_f32_16x16x32_bf16(kf, qa[2 * p + 1][ks], sc[n][1], 0, 0, 0);
        }
      }
      __builtin_amdgcn_s_setprio(0);
#pragma unroll
      for (int f = 0; f < 2; f++) {
        const int ff = 2 * p + f;
        const int jtEnd = (p == 0) ? JT_A : JT_B;
        const bool diag = (jt == jtEnd - 1);
        float pv[4][4];
#pragma unroll
        for (int n = 0; n < 4; n++)
#pragma unroll
          for (int r = 0; r < 4; r++)
            pv[n][r] = exp2f(fmaf(sc[n][f][r], SCL2E, -12.0f));
        if (diag) {
#pragma unroll
          for (int n = 0; n < 4; n++)
#pragma unroll
            for (int r = 0; r < 4; r++)
              if ((j0 + n * 16 + 4 * g + r) > rowq[ff]) pv[n][r] = 0.f;
        }
        u32* pw32 = reinterpret_cast<u32*>(Ps[wave][f]);
#pragma unroll
        for (int n = 0; n < 4; n++) {
          union { u32 w; u16 hh[2]; } c01, c23;
          c01.hh[0] = f2bf(pv[n][0]); c01.hh[1] = f2bf(pv[n][1]);
          c23.hh[0] = f2bf(pv[n][2]); c23.hh[1] = f2bf(pv[n][3]);
          const int idx = ql * 32 + (((n << 3) + (g << 1)) ^ xsw2);
          pw32[idx] = c01.w;
          pw32[idx + 1] = c23.w;
        }
      }
#pragma unroll
      for (int f = 0; f < 2; f++)
#pragma unroll
        for (int ks = 0; ks < 2; ks++)
          pa[2 * p + f][ks] = *reinterpret_cast<const short8*>(
              Ps[wave][f] + ql * 64 + ((32 * ks + 8 * g) ^ (xsw2 << 1)));
    }

    // O^T += V^T·P^T ; denominator row via ones-MFMA
    __builtin_amdgcn_s_setprio(1);
#pragma unroll
    for (int ks = 0; ks < 2; ks++) {
      const int sd = ks * 4 + g;
#pragma unroll
      for (int dn = 0; dn < 4; dn++) {
        const int vr = dn * 16 + ql;
        short8 vf = *reinterpret_cast<const short8*>(vsb + vr * 64 + ((sd ^ (vr & 7)) << 3));
        if (actA) {
          oacc[dn][0] = __builtin_amdgcn_mfma_f32_16x16x32_bf16(vf, pa[0][ks], oacc[dn][0], 0, 0, 0);
          oacc[dn][1] = __builtin_amdgcn_mfma_f32_16x16x32_bf16(vf, pa[1][ks], oacc[dn][1], 0, 0, 0);
        }
        oacc[dn][2] = __builtin_amdgcn_mfma_f32_16x16x32_bf16(vf, pa[2][ks], oacc[dn][2], 0, 0, 0);
        oacc[dn][3] = __builtin_amdgcn_mfma_f32_16x16x32_bf16(vf, pa[3][ks], oacc[dn][3], 0, 0, 0);
      }
      if (actA) {
        sacc[0] = __builtin_amdgcn_mfma_f32_16x16x32_bf16(ones_af, pa[0][ks], sacc[0], 0, 0, 0);
        sacc[1] = __builtin_amdgcn_mfma_f32_16x16x32_bf16(ones_af, pa[1][ks], sacc[1], 0, 0, 0);
      }
      sacc[2] = __builtin_amdgcn_mfma_f32_16x16x32_bf16(ones_af, pa[2][ks], sacc[2], 0, 0, 0);
      sacc[3] = __builtin_amdgcn_mfma_f32_16x16x32_bf16(ones_af, pa[3][ks], sacc[3], 0, 0, 0);
    }
    __builtin_amdgcn_s_setprio(0);

    __syncthreads();  // stage(jt+1) drained + all reads of buf[cur] done
    cur ^= 1;
  }

  // output: denominator sits in sacc[ff][0] on lanes g==0 (row 0, col ql);
  // broadcast to the 4 lanes of each column via __shfl(lane index = ql)
#pragma unroll
  for (int ff = 0; ff < 4; ff++) {
    const float s = __shfl(sacc[ff][0], ql);
    const float il = 1.0f / s;
#pragma unroll
    for (int dn = 0; dn < 4; dn++) {
      union { short4v v; u16 uu[4]; } o;
#pragma unroll
      for (int r = 0; r < 4; r++) o.uu[r] = f2bf(oacc[dn][ff][r] * il);
      u16* dst = Aout + ((size_t)b * S_ + rowq[ff]) * D_ + h * HD_ + dn * 16 + 4 * g;
      *reinterpret_cast<short4v*>(dst) = o.v;
    }
  }
}

// ---------------- launcher ----------------
extern "C" void kernel_launch(void* const* d_in, const int* in_sizes, int n_in,
                              void* d_out, int out_size, void* d_ws,
                              size_t ws_size, hipStream_t stream) {
  const float* x = (const float*)d_in[0];
  const float* wqkv = (const float*)d_in[1];
  const float* wout = (const float*)d_in[2];
  const float* gain = (const float*)d_in[3];

  float* out_attn = (float*)d_out;                       // (B,S,D) f32
  float* out_vflat = out_attn + (size_t)B_ * S_ * D_;    // (H*B,S,HD) f32

  uint8_t* w = (uint8_t*)d_ws;
  u16* xb     = (u16*)(w);                      // 16,777,216 B
  u16* wqkvb  = (u16*)(w + 16777216);           // 12,582,912 B
  u16* woutb  = (u16*)(w + 29360128);           //  8,388,608 B
  float* proj = (float*)(w + 37748736);         // 50,331,648 B
  u16* Qn     = (u16*)(w + 88080384);           // 16,777,216 B
  u16* Kn     = (u16*)(w + 104857600);          //  4,194,304 B
  u16* Vt     = (u16*)(w + 109051904);          //  4,194,304 B
  u16* attnb  = (u16*)(w + 113246208);          // 16,777,216 B
  float* tc   = (float*)(w + 130023424);        //    262,144 B
  float* ts   = (float*)(w + 130285568);        //    262,144 B
  // total: 130,547,712 B

  pack_bf16<<<4096, 256, 0, stream>>>(x, xb, B_ * S_ * D_);
  pack_bf16<<<3072, 256, 0, stream>>>(wqkv, wqkvb, PROJN * D_);
  pack_bf16<<<2048, 256, 0, stream>>>(wout, woutb, D_ * D_);
  rope_table<<<256, 256, 0, stream>>>(tc, ts);

  // proj = x @ w_qkv^T : (4096 x 3072)
  gemm_bt<<<(4096 / 128) * (3072 / 128), 256, 0, stream>>>(xb, wqkvb, proj,
                                                           4096, PROJN, 2048);
  rope_norm<<<(B_ * S_ * 40) / 4, 256, 0, stream>>>(proj, tc, ts, gain, Qn, Kn);
  vtrans<<<B_ * KVH_ * (S_ / 64), 256, 0, stream>>>(proj, Vt, out_vflat);
  // one block per q-tile PAIR: B_*KVH_*32 blocks
  attn_fwd<<<B_ * KVH_ * (S_ / 64), 256, 0, stream>>>(Qn, Kn, Vt, attnb);
  // attn_out = attn @ w_out^T : (4096 x 2048)
  gemm_bt<<<(4096 / 128) * (2048 / 128), 256, 0, stream>>>(attnb, woutb,
                                                           out_attn, 4096,
                                                           2048, 2048);
}

// Round 9
// 292.215 us; speedup vs baseline: 1.0897x; 1.0897x over previous
//
#include <hip/hip_runtime.h>
#include <hip/hip_bf16.h>
#include <cstdint>
#include <cstddef>

#define B_ 2
#define S_ 2048
#define D_ 2048
#define H_ 32
#define KVH_ 8
#define HD_ 64
#define PROJN 3072   // Q_OUT(2048) + 2*KV_OUT(512)

typedef unsigned short u16;
typedef unsigned int u32;
typedef __attribute__((ext_vector_type(8))) short short8;
typedef __attribute__((ext_vector_type(4))) short short4v;
typedef __attribute__((ext_vector_type(4))) float f32x4;

__device__ __forceinline__ u16 f2bf(float f) {
  __hip_bfloat16 h = __float2bfloat16(f);
  return *reinterpret_cast<u16*>(&h);
}

#define GLDS16(g, l)                                                           \
  __builtin_amdgcn_global_load_lds(                                            \
      (const __attribute__((address_space(1))) void*)(g),                      \
      (__attribute__((address_space(3))) void*)(l), 16, 0, 0)

// ---------------- pack f32 -> bf16 ----------------
__global__ __launch_bounds__(256) void pack_bf16(const float* __restrict__ in,
                                                 u16* __restrict__ out, int n) {
  int i = (blockIdx.x * 256 + threadIdx.x) * 8;
  if (i >= n) return;
  const float4* p = reinterpret_cast<const float4*>(in + i);
  float4 a = p[0], b = p[1];
  union { short8 v; u16 u[8]; } r;
  r.u[0] = f2bf(a.x); r.u[1] = f2bf(a.y); r.u[2] = f2bf(a.z); r.u[3] = f2bf(a.w);
  r.u[4] = f2bf(b.x); r.u[5] = f2bf(b.y); r.u[6] = f2bf(b.z); r.u[7] = f2bf(b.w);
  *reinterpret_cast<short8*>(out + i) = r.v;
}

// ---------------- rope cos/sin table ----------------
__global__ __launch_bounds__(256) void rope_table(float* __restrict__ tc,
                                                  float* __restrict__ ts) {
  int i = blockIdx.x * 256 + threadIdx.x;  // S_*32
  int s = i >> 5, j = i & 31;
  float e = (float)(2 * j) / 64.0f;
  float inv_freq = 1.0f / powf(10000.0f, e);
  float ang = (float)s * inv_freq;
  tc[i] = cosf(ang);
  ts[i] = sinf(ang);
}

// ---------------- bf16 GEMM: C[M,N] = A[M,K] * Bw[N,K]^T ----------------
__global__ __launch_bounds__(256) void gemm_bt(const u16* __restrict__ A,
                                               const u16* __restrict__ Bw,
                                               float* __restrict__ C, int M,
                                               int N, int K) {
  __shared__ u16 As[128 * 64];
  __shared__ u16 Bs[128 * 64];
  const int tid = threadIdx.x;
  const int lane = tid & 63;
  const int wave = tid >> 6;
  const int ntile = N >> 7;
  const int m0 = (blockIdx.x / ntile) << 7;
  const int n0 = (blockIdx.x % ntile) << 7;
  const int wr = (wave >> 1) << 6;
  const int wc = (wave & 1) << 6;
  const int arow = lane & 15;
  const int kgrp = lane >> 4;

  const f32x4 zero4 = {0.f, 0.f, 0.f, 0.f};
  f32x4 acc[4][4];
#pragma unroll
  for (int m = 0; m < 4; m++)
#pragma unroll
    for (int n = 0; n < 4; n++) acc[m][n] = zero4;

  int srow[4], sslot[4];
#pragma unroll
  for (int i = 0; i < 4; i++) {
    int c = i * 256 + tid;
    srow[i] = c >> 3;
    sslot[i] = (c & 7) ^ (srow[i] & 7);  // inverse-swizzled source slot
  }

  auto stage = [&](int kt) {
    const int k0 = kt << 6;
#pragma unroll
    for (int i = 0; i < 4; i++) {
      const u16* ga = A + (size_t)(m0 + srow[i]) * K + k0 + sslot[i] * 8;
      GLDS16(ga, As + (i * 256 + tid) * 8);
    }
#pragma unroll
    for (int i = 0; i < 4; i++) {
      const u16* gb = Bw + (size_t)(n0 + srow[i]) * K + k0 + sslot[i] * 8;
      GLDS16(gb, Bs + (i * 256 + tid) * 8);
    }
  };

  const int KT = K >> 6;
  stage(0);
  for (int kt = 0;; kt++) {
    __syncthreads();  // staging drained (compiler emits vmcnt(0) before barrier)
#pragma unroll
    for (int ks = 0; ks < 2; ks++) {
      const int sd = ks * 4 + kgrp;
      short8 a[4], b[4];
#pragma unroll
      for (int m = 0; m < 4; m++) {
        int r = wr + m * 16 + arow;
        a[m] = *reinterpret_cast<const short8*>(As + r * 64 + ((sd ^ (r & 7)) << 3));
      }
#pragma unroll
      for (int n = 0; n < 4; n++) {
        int r = wc + n * 16 + arow;
        b[n] = *reinterpret_cast<const short8*>(Bs + r * 64 + ((sd ^ (r & 7)) << 3));
      }
#pragma unroll
      for (int m = 0; m < 4; m++)
#pragma unroll
        for (int n = 0; n < 4; n++)
          acc[m][n] = __builtin_amdgcn_mfma_f32_16x16x32_bf16(a[m], b[n], acc[m][n], 0, 0, 0);
    }
    if (kt + 1 == KT) break;
    __syncthreads();
    stage(kt + 1);
  }

  const int crow = kgrp * 4;
#pragma unroll
  for (int m = 0; m < 4; m++) {
#pragma unroll
    for (int n = 0; n < 4; n++) {
      float* cp = C + (size_t)(m0 + wr + m * 16 + crow) * N + n0 + wc + n * 16 + arow;
#pragma unroll
      for (int r = 0; r < 4; r++) cp[(size_t)r * N] = acc[m][n][r];
    }
  }
}

// ---------------- RoPE + RMSNorm for Q and K ----------------
// one wave per (b, s, head'), head' in [0,40): 0..31 Q heads, 32..39 K heads
__global__ __launch_bounds__(256) void rope_norm(
    const float* __restrict__ proj, const float* __restrict__ tc,
    const float* __restrict__ ts, const float* __restrict__ gain,
    u16* __restrict__ Qn, u16* __restrict__ Kn) {
  int wid = (blockIdx.x * 256 + threadIdx.x) >> 6;  // B_*S_*40 waves
  int lane = threadIdx.x & 63;
  int hh = wid % 40;
  int bs = wid / 40;  // b*S_ + s
  int s = bs & (S_ - 1);
  int b = bs >> 11;
  int off = hh < 32 ? hh * 64 + lane : 2048 + (hh - 32) * 64 + lane;
  float val = proj[(size_t)bs * PROJN + off];
  int j = lane & 31;
  float c = tc[s * 32 + j], sn = ts[s * 32 + j];
  float partner = __shfl_xor(val, 32);
  float out = lane < 32 ? val * c - partner * sn : val * c + partner * sn;
  float ss = out * out;
#pragma unroll
  for (int m = 32; m >= 1; m >>= 1) ss += __shfl_xor(ss, m);
  float inv = rsqrtf(ss * (1.0f / 64.0f) + 1e-6f);
  float g = hh < 32 ? gain[0] : 1.0f;
  u16 ub = f2bf(out * inv * g);
  if (hh < 32)
    Qn[(((size_t)(b * H_ + hh)) * S_ + s) * HD_ + lane] = ub;
  else
    Kn[(((size_t)(b * KVH_ + (hh - 32))) * S_ + s) * HD_ + lane] = ub;
}

// ---------------- V: transpose to (B,KVH,HD,S) bf16 + V_flat f32 output ----------------
__global__ __launch_bounds__(256) void vtrans(const float* __restrict__ proj,
                                              u16* __restrict__ Vt,
                                              float* __restrict__ Vout) {
  __shared__ float tile[64][65];
  const int bid = blockIdx.x;  // B_*KVH_*(S_/64)
  const int st = bid & 31;
  const int s0 = st << 6;
  const int kvh = (bid >> 5) & 7;
  const int b = bid >> 8;
  const int t = threadIdx.x;
  const int sr = t >> 2;
  const int d0 = (t & 3) << 4;
  const float* src = proj + ((size_t)(b * S_ + s0 + sr)) * PROJN + 2560 + kvh * 64 + d0;
  float v[16];
#pragma unroll
  for (int i = 0; i < 16; i += 4) {
    float4 x = *reinterpret_cast<const float4*>(src + i);
    v[i] = x.x; v[i + 1] = x.y; v[i + 2] = x.z; v[i + 3] = x.w;
  }
  // V_flat output: rows h*B+b, 4 repeated heads (scale rsqrt(1+1e-8) == 1.0f exactly)
#pragma unroll
  for (int hh = 0; hh < 4; hh++) {
    int hq = kvh * 4 + hh;
    float* dst = Vout + (((size_t)(hq * B_ + b)) * S_ + s0 + sr) * HD_ + d0;
#pragma unroll
    for (int i = 0; i < 16; i += 4)
      *reinterpret_cast<float4*>(dst + i) = make_float4(v[i], v[i + 1], v[i + 2], v[i + 3]);
  }
#pragma unroll
  for (int i = 0; i < 16; i++) tile[sr][d0 + i] = v[i];
  __syncthreads();
  const int d = t >> 2;
  const int sc = (t & 3) << 4;
  union { short8 v8; u16 u[8]; } o0, o1;
#pragma unroll
  for (int i = 0; i < 8; i++) o0.u[i] = f2bf(tile[sc + i][d]);
#pragma unroll
  for (int i = 0; i < 8; i++) o1.u[i] = f2bf(tile[sc + 8 + i][d]);
  u16* dst = Vt + (((size_t)(b * KVH_ + kvh)) * HD_ + d) * S_ + s0 + sc;
  *reinterpret_cast<short8*>(dst) = o0.v8;
  *reinterpret_cast<short8*>(dst + 8) = o1.v8;
}

// ---------------- flash attention (causal, GQA) ----------------
// Block = (b, kvh, q-tile PAIR {u, 63-u}). FIXED-C softmax (see R6 comment).
// R9: Ps[wave][2] (48KB LDS total -> 3 blocks/CU, launch_bounds(256,3));
// denominator stays VALU psum (R8's ones-MFMA caused register spill: VGPR
// capped at 170 by 3-wave bound, sacc+pa live ranges overflowed -> 274MB
// scratch writes). pa read inside p-loop (wave-private buffer, DS in-order).
__global__ __launch_bounds__(256, 3) void attn_fwd(const u16* __restrict__ Qn,
                                                   const u16* __restrict__ Kn,
                                                   const u16* __restrict__ Vt,
                                                   u16* __restrict__ Aout) {
  __shared__ u16 Ks[2][64 * 64];
  __shared__ u16 Vs[2][64 * 64];
  __shared__ u16 Ps[4][2][1024];  // [wave][half-frag][16 q-rows x 64 kv]
  const int bid = blockIdx.x;     // B_*KVH_*32
  const int u = bid & 31;
  const int kvh = (bid >> 5) & 7;
  const int b = bid >> 8;
  const int q0A = u << 5;
  const int q0B = (63 - u) << 5;
  const int JT_A = (u >> 1) + 1;
  const int JT_B = 32 - (u >> 1);
  const int tid = threadIdx.x;
  const int lane = tid & 63;
  const int wave = tid >> 6;
  const int h = kvh * 4 + wave;  // this wave's Q head
  const int ql = lane & 15;
  const int g = lane >> 4;
  const float SCL2E = 0.125f * 1.44269504088896340736f;

  // Q frags: ff=0,1 -> tile A rows q0A+16*ff+ql; ff=2,3 -> tile B
  short8 qa[4][2];
  int rowq[4];
#pragma unroll
  for (int ff = 0; ff < 4; ff++) {
    const int q0 = (ff < 2) ? q0A : q0B;
    rowq[ff] = q0 + 16 * (ff & 1) + ql;
    const u16* qb = Qn + (((size_t)(b * H_ + h)) * S_ + rowq[ff]) * HD_;
    qa[ff][0] = *reinterpret_cast<const short8*>(qb + g * 8);
    qa[ff][1] = *reinterpret_cast<const short8*>(qb + 32 + g * 8);
  }

  const f32x4 zero4 = {0.f, 0.f, 0.f, 0.f};
  f32x4 oacc[4][4];  // [dn][ff]
#pragma unroll
  for (int dn = 0; dn < 4; dn++)
#pragma unroll
    for (int ff = 0; ff < 4; ff++) oacc[dn][ff] = zero4;
  float psum[4] = {0.f, 0.f, 0.f, 0.f};

  const u16* kg = Kn + ((size_t)(b * KVH_ + kvh)) * S_ * HD_;
  const u16* vg = Vt + ((size_t)(b * KVH_ + kvh)) * HD_ * S_;

  const int c0 = tid, c1 = 256 + tid;
  const int r0 = c0 >> 3, sl0 = (c0 & 7) ^ (r0 & 7);
  const int r1 = c1 >> 3, sl1 = (c1 & 7) ^ (r1 & 7);
  const int xsw2 = (ql & 7) << 2;

  auto stage = [&](int jt, int buf) {
    const int j0 = jt << 6;
    GLDS16(kg + (size_t)(j0 + r0) * HD_ + sl0 * 8, Ks[buf] + c0 * 8);
    GLDS16(kg + (size_t)(j0 + r1) * HD_ + sl1 * 8, Ks[buf] + c1 * 8);
    GLDS16(vg + (size_t)r0 * S_ + j0 + sl0 * 8, Vs[buf] + c0 * 8);
    GLDS16(vg + (size_t)r1 * S_ + j0 + sl1 * 8, Vs[buf] + c1 * 8);
  };

  stage(0, 0);
  __syncthreads();  // drain prologue stage
  int cur = 0;
  for (int jt = 0; jt < JT_B; jt++) {
    if (jt + 1 < JT_B) stage(jt + 1, cur ^ 1);  // issue next tile early
    const int j0 = jt << 6;
    const u16* ksb = Ks[cur];
    const u16* vsb = Vs[cur];
    const bool actA = (jt < JT_A);

    short8 pa[4][2];
    // per q-tile pair: S^T = K·Q^T, then p = exp2(fma(s,SCL2E,-12)), pack->LDS,
    // read back B-frags (wave-private buffer, DS ops in-order per wave)
#pragma unroll
    for (int p = 0; p < 2; p++) {
      if (p == 0 && !actA) continue;
      f32x4 sc[4][2];
#pragma unroll
      for (int n = 0; n < 4; n++)
#pragma unroll
        for (int f = 0; f < 2; f++) sc[n][f] = zero4;
      __builtin_amdgcn_s_setprio(1);
#pragma unroll
      for (int ks = 0; ks < 2; ks++) {
        const int sd = ks * 4 + g;
#pragma unroll
        for (int n = 0; n < 4; n++) {
          const int r = n * 16 + ql;
          short8 kf = *reinterpret_cast<const short8*>(ksb + r * 64 + ((sd ^ (r & 7)) << 3));
          sc[n][0] = __builtin_amdgcn_mfma_f32_16x16x32_bf16(kf, qa[2 * p][ks], sc[n][0], 0, 0, 0);
          sc[n][1] = __builtin_amdgcn_mfma_f32_16x16x32_bf16(kf, qa[2 * p + 1][ks], sc[n][1], 0, 0, 0);
        }
      }
      __builtin_amdgcn_s_setprio(0);
#pragma unroll
      for (int f = 0; f < 2; f++) {
        const int ff = 2 * p + f;
        const int jtEnd = (p == 0) ? JT_A : JT_B;
        const bool diag = (jt == jtEnd - 1);
        float pv[4][4];
#pragma unroll
        for (int n = 0; n < 4; n++)
#pragma unroll
          for (int r = 0; r < 4; r++)
            pv[n][r] = exp2f(fmaf(sc[n][f][r], SCL2E, -12.0f));
        if (diag) {
#pragma unroll
          for (int n = 0; n < 4; n++)
#pragma unroll
            for (int r = 0; r < 4; r++)
              if ((j0 + n * 16 + 4 * g + r) > rowq[ff]) pv[n][r] = 0.f;
        }
        u32* pw32 = reinterpret_cast<u32*>(Ps[wave][f]);
#pragma unroll
        for (int n = 0; n < 4; n++) {
          psum[ff] += (pv[n][0] + pv[n][1]) + (pv[n][2] + pv[n][3]);
          union { u32 w; u16 hh[2]; } c01, c23;
          c01.hh[0] = f2bf(pv[n][0]); c01.hh[1] = f2bf(pv[n][1]);
          c23.hh[0] = f2bf(pv[n][2]); c23.hh[1] = f2bf(pv[n][3]);
          const int idx = ql * 32 + (((n << 3) + (g << 1)) ^ xsw2);
          pw32[idx] = c01.w;
          pw32[idx + 1] = c23.w;
        }
      }
#pragma unroll
      for (int f = 0; f < 2; f++)
#pragma unroll
        for (int ks = 0; ks < 2; ks++)
          pa[2 * p + f][ks] = *reinterpret_cast<const short8*>(
              Ps[wave][f] + ql * 64 + ((32 * ks + 8 * g) ^ (xsw2 << 1)));
    }

    // O^T += V^T · P^T (vf shared across frags)
    __builtin_amdgcn_s_setprio(1);
#pragma unroll
    for (int ks = 0; ks < 2; ks++) {
      const int sd = ks * 4 + g;
#pragma unroll
      for (int dn = 0; dn < 4; dn++) {
        const int vr = dn * 16 + ql;
        short8 vf = *reinterpret_cast<const short8*>(vsb + vr * 64 + ((sd ^ (vr & 7)) << 3));
        if (actA) {
          oacc[dn][0] = __builtin_amdgcn_mfma_f32_16x16x32_bf16(vf, pa[0][ks], oacc[dn][0], 0, 0, 0);
          oacc[dn][1] = __builtin_amdgcn_mfma_f32_16x16x32_bf16(vf, pa[1][ks], oacc[dn][1], 0, 0, 0);
        }
        oacc[dn][2] = __builtin_amdgcn_mfma_f32_16x16x32_bf16(vf, pa[2][ks], oacc[dn][2], 0, 0, 0);
        oacc[dn][3] = __builtin_amdgcn_mfma_f32_16x16x32_bf16(vf, pa[3][ks], oacc[dn][3], 0, 0, 0);
      }
    }
    __builtin_amdgcn_s_setprio(0);

    __syncthreads();  // stage(jt+1) drained + all reads of buf[cur] done
    cur ^= 1;
  }

  // final denominator reduce (once) + output
#pragma unroll
  for (int ff = 0; ff < 4; ff++) {
    float s = psum[ff];
    s += __shfl_xor(s, 16);
    s += __shfl_xor(s, 32);
    const float il = 1.0f / s;
#pragma unroll
    for (int dn = 0; dn < 4; dn++) {
      union { short4v v; u16 uu[4]; } o;
#pragma unroll
      for (int r = 0; r < 4; r++) o.uu[r] = f2bf(oacc[dn][ff][r] * il);
      u16* dst = Aout + ((size_t)b * S_ + rowq[ff]) * D_ + h * HD_ + dn * 16 + 4 * g;
      *reinterpret_cast<short4v*>(dst) = o.v;
    }
  }
}

// ---------------- launcher ----------------
extern "C" void kernel_launch(void* const* d_in, const int* in_sizes, int n_in,
                              void* d_out, int out_size, void* d_ws,
                              size_t ws_size, hipStream_t stream) {
  const float* x = (const float*)d_in[0];
  const float* wqkv = (const float*)d_in[1];
  const float* wout = (const float*)d_in[2];
  const float* gain = (const float*)d_in[3];

  float* out_attn = (float*)d_out;                       // (B,S,D) f32
  float* out_vflat = out_attn + (size_t)B_ * S_ * D_;    // (H*B,S,HD) f32

  uint8_t* w = (uint8_t*)d_ws;
  u16* xb     = (u16*)(w);                      // 16,777,216 B
  u16* wqkvb  = (u16*)(w + 16777216);           // 12,582,912 B
  u16* woutb  = (u16*)(w + 29360128);           //  8,388,608 B
  float* proj = (float*)(w + 37748736);         // 50,331,648 B
  u16* Qn     = (u16*)(w + 88080384);           // 16,777,216 B
  u16* Kn     = (u16*)(w + 104857600);          //  4,194,304 B
  u16* Vt     = (u16*)(w + 109051904);          //  4,194,304 B
  u16* attnb  = (u16*)(w + 113246208);          // 16,777,216 B
  float* tc   = (float*)(w + 130023424);        //    262,144 B
  float* ts   = (float*)(w + 130285568);        //    262,144 B
  // total: 130,547,712 B

  pack_bf16<<<4096, 256, 0, stream>>>(x, xb, B_ * S_ * D_);
  pack_bf16<<<3072, 256, 0, stream>>>(wqkv, wqkvb, PROJN * D_);
  pack_bf16<<<2048, 256, 0, stream>>>(wout, woutb, D_ * D_);
  rope_table<<<256, 256, 0, stream>>>(tc, ts);

  // proj = x @ w_qkv^T : (4096 x 3072)
  gemm_bt<<<(4096 / 128) * (3072 / 128), 256, 0, stream>>>(xb, wqkvb, proj,
                                                           4096, PROJN, 2048);
  rope_norm<<<(B_ * S_ * 40) / 4, 256, 0, stream>>>(proj, tc, ts, gain, Qn, Kn);
  vtrans<<<B_ * KVH_ * (S_ / 64), 256, 0, stream>>>(proj, Vt, out_vflat);
  // one block per q-tile PAIR: B_*KVH_*32 blocks
  attn_fwd<<<B_ * KVH_ * (S_ / 64), 256, 0, stream>>>(Qn, Kn, Vt, attnb);
  // attn_out = attn @ w_out^T : (4096 x 2048)
  gemm_bt<<<(4096 / 128) * (2048 / 128), 256, 0, stream>>>(attnb, woutb,
                                                           out_attn, 4096,
                                                           2048, 2048);
}

// Round 10
// 252.678 us; speedup vs baseline: 1.2602x; 1.1565x over previous
//
#include <hip/hip_runtime.h>
#include <hip/hip_bf16.h>
#include <cstdint>
#include <cstddef>

#define B_ 2
#define S_ 2048
#define D_ 2048
#define H_ 32
#define KVH_ 8
#define HD_ 64
#define PROJN 3072   // Q_OUT(2048) + 2*KV_OUT(512)

typedef unsigned short u16;
typedef unsigned int u32;
typedef __attribute__((ext_vector_type(8))) short short8;
typedef __attribute__((ext_vector_type(4))) short short4v;
typedef __attribute__((ext_vector_type(4))) float f32x4;

__device__ __forceinline__ u16 f2bf(float f) {
  __hip_bfloat16 h = __float2bfloat16(f);
  return *reinterpret_cast<u16*>(&h);
}

#define GLDS16(g, l)                                                           \
  __builtin_amdgcn_global_load_lds(                                            \
      (const __attribute__((address_space(1))) void*)(g),                      \
      (__attribute__((address_space(3))) void*)(l), 16, 0, 0)

// ---------------- pack f32 -> bf16 ----------------
__global__ __launch_bounds__(256) void pack_bf16(const float* __restrict__ in,
                                                 u16* __restrict__ out, int n) {
  int i = (blockIdx.x * 256 + threadIdx.x) * 8;
  if (i >= n) return;
  const float4* p = reinterpret_cast<const float4*>(in + i);
  float4 a = p[0], b = p[1];
  union { short8 v; u16 u[8]; } r;
  r.u[0] = f2bf(a.x); r.u[1] = f2bf(a.y); r.u[2] = f2bf(a.z); r.u[3] = f2bf(a.w);
  r.u[4] = f2bf(b.x); r.u[5] = f2bf(b.y); r.u[6] = f2bf(b.z); r.u[7] = f2bf(b.w);
  *reinterpret_cast<short8*>(out + i) = r.v;
}

// ---------------- rope cos/sin table ----------------
__global__ __launch_bounds__(256) void rope_table(float* __restrict__ tc,
                                                  float* __restrict__ ts) {
  int i = blockIdx.x * 256 + threadIdx.x;  // S_*32
  int s = i >> 5, j = i & 31;
  float e = (float)(2 * j) / 64.0f;
  float inv_freq = 1.0f / powf(10000.0f, e);
  float ang = (float)s * inv_freq;
  tc[i] = cosf(ang);
  ts[i] = sinf(ang);
}

// ---------------- bf16 GEMM: C[M,N] = A[M,K] * Bw[N,K]^T ----------------
__global__ __launch_bounds__(256) void gemm_bt(const u16* __restrict__ A,
                                               const u16* __restrict__ Bw,
                                               float* __restrict__ C, int M,
                                               int N, int K) {
  __shared__ u16 As[128 * 64];
  __shared__ u16 Bs[128 * 64];
  const int tid = threadIdx.x;
  const int lane = tid & 63;
  const int wave = tid >> 6;
  const int ntile = N >> 7;
  const int m0 = (blockIdx.x / ntile) << 7;
  const int n0 = (blockIdx.x % ntile) << 7;
  const int wr = (wave >> 1) << 6;
  const int wc = (wave & 1) << 6;
  const int arow = lane & 15;
  const int kgrp = lane >> 4;

  const f32x4 zero4 = {0.f, 0.f, 0.f, 0.f};
  f32x4 acc[4][4];
#pragma unroll
  for (int m = 0; m < 4; m++)
#pragma unroll
    for (int n = 0; n < 4; n++) acc[m][n] = zero4;

  int srow[4], sslot[4];
#pragma unroll
  for (int i = 0; i < 4; i++) {
    int c = i * 256 + tid;
    srow[i] = c >> 3;
    sslot[i] = (c & 7) ^ (srow[i] & 7);  // inverse-swizzled source slot
  }

  auto stage = [&](int kt) {
    const int k0 = kt << 6;
#pragma unroll
    for (int i = 0; i < 4; i++) {
      const u16* ga = A + (size_t)(m0 + srow[i]) * K + k0 + sslot[i] * 8;
      GLDS16(ga, As + (i * 256 + tid) * 8);
    }
#pragma unroll
    for (int i = 0; i < 4; i++) {
      const u16* gb = Bw + (size_t)(n0 + srow[i]) * K + k0 + sslot[i] * 8;
      GLDS16(gb, Bs + (i * 256 + tid) * 8);
    }
  };

  const int KT = K >> 6;
  stage(0);
  for (int kt = 0;; kt++) {
    __syncthreads();  // staging drained (compiler emits vmcnt(0) before barrier)
#pragma unroll
    for (int ks = 0; ks < 2; ks++) {
      const int sd = ks * 4 + kgrp;
      short8 a[4], b[4];
#pragma unroll
      for (int m = 0; m < 4; m++) {
        int r = wr + m * 16 + arow;
        a[m] = *reinterpret_cast<const short8*>(As + r * 64 + ((sd ^ (r & 7)) << 3));
      }
#pragma unroll
      for (int n = 0; n < 4; n++) {
        int r = wc + n * 16 + arow;
        b[n] = *reinterpret_cast<const short8*>(Bs + r * 64 + ((sd ^ (r & 7)) << 3));
      }
#pragma unroll
      for (int m = 0; m < 4; m++)
#pragma unroll
        for (int n = 0; n < 4; n++)
          acc[m][n] = __builtin_amdgcn_mfma_f32_16x16x32_bf16(a[m], b[n], acc[m][n], 0, 0, 0);
    }
    if (kt + 1 == KT) break;
    __syncthreads();
    stage(kt + 1);
  }

  const int crow = kgrp * 4;
#pragma unroll
  for (int m = 0; m < 4; m++) {
#pragma unroll
    for (int n = 0; n < 4; n++) {
      float* cp = C + (size_t)(m0 + wr + m * 16 + crow) * N + n0 + wc + n * 16 + arow;
#pragma unroll
      for (int r = 0; r < 4; r++) cp[(size_t)r * N] = acc[m][n][r];
    }
  }
}

// ---------------- RoPE + RMSNorm for Q and K ----------------
// one wave per (b, s, head'), head' in [0,40): 0..31 Q heads, 32..39 K heads
__global__ __launch_bounds__(256) void rope_norm(
    const float* __restrict__ proj, const float* __restrict__ tc,
    const float* __restrict__ ts, const float* __restrict__ gain,
    u16* __restrict__ Qn, u16* __restrict__ Kn) {
  int wid = (blockIdx.x * 256 + threadIdx.x) >> 6;  // B_*S_*40 waves
  int lane = threadIdx.x & 63;
  int hh = wid % 40;
  int bs = wid / 40;  // b*S_ + s
  int s = bs & (S_ - 1);
  int b = bs >> 11;
  int off = hh < 32 ? hh * 64 + lane : 2048 + (hh - 32) * 64 + lane;
  float val = proj[(size_t)bs * PROJN + off];
  int j = lane & 31;
  float c = tc[s * 32 + j], sn = ts[s * 32 + j];
  float partner = __shfl_xor(val, 32);
  float out = lane < 32 ? val * c - partner * sn : val * c + partner * sn;
  float ss = out * out;
#pragma unroll
  for (int m = 32; m >= 1; m >>= 1) ss += __shfl_xor(ss, m);
  float inv = rsqrtf(ss * (1.0f / 64.0f) + 1e-6f);
  float g = hh < 32 ? gain[0] : 1.0f;
  u16 ub = f2bf(out * inv * g);
  if (hh < 32)
    Qn[(((size_t)(b * H_ + hh)) * S_ + s) * HD_ + lane] = ub;
  else
    Kn[(((size_t)(b * KVH_ + (hh - 32))) * S_ + s) * HD_ + lane] = ub;
}

// ---------------- V: transpose to (B,KVH,HD,S) bf16 + V_flat f32 output ----------------
__global__ __launch_bounds__(256) void vtrans(const float* __restrict__ proj,
                                              u16* __restrict__ Vt,
                                              float* __restrict__ Vout) {
  __shared__ float tile[64][65];
  const int bid = blockIdx.x;  // B_*KVH_*(S_/64)
  const int st = bid & 31;
  const int s0 = st << 6;
  const int kvh = (bid >> 5) & 7;
  const int b = bid >> 8;
  const int t = threadIdx.x;
  const int sr = t >> 2;
  const int d0 = (t & 3) << 4;
  const float* src = proj + ((size_t)(b * S_ + s0 + sr)) * PROJN + 2560 + kvh * 64 + d0;
  float v[16];
#pragma unroll
  for (int i = 0; i < 16; i += 4) {
    float4 x = *reinterpret_cast<const float4*>(src + i);
    v[i] = x.x; v[i + 1] = x.y; v[i + 2] = x.z; v[i + 3] = x.w;
  }
  // V_flat output: rows h*B+b, 4 repeated heads (scale rsqrt(1+1e-8) == 1.0f exactly)
#pragma unroll
  for (int hh = 0; hh < 4; hh++) {
    int hq = kvh * 4 + hh;
    float* dst = Vout + (((size_t)(hq * B_ + b)) * S_ + s0 + sr) * HD_ + d0;
#pragma unroll
    for (int i = 0; i < 16; i += 4)
      *reinterpret_cast<float4*>(dst + i) = make_float4(v[i], v[i + 1], v[i + 2], v[i + 3]);
  }
#pragma unroll
  for (int i = 0; i < 16; i++) tile[sr][d0 + i] = v[i];
  __syncthreads();
  const int d = t >> 2;
  const int sc = (t & 3) << 4;
  union { short8 v8; u16 u[8]; } o0, o1;
#pragma unroll
  for (int i = 0; i < 8; i++) o0.u[i] = f2bf(tile[sc + i][d]);
#pragma unroll
  for (int i = 0; i < 8; i++) o1.u[i] = f2bf(tile[sc + 8 + i][d]);
  u16* dst = Vt + (((size_t)(b * KVH_ + kvh)) * HD_ + d) * S_ + s0 + sc;
  *reinterpret_cast<short8*>(dst) = o0.v8;
  *reinterpret_cast<short8*>(dst + 8) = o1.v8;
}

// ---------------- flash attention (causal, GQA) ----------------
// Block = (b, kvh, q-tile PAIR {u, 63-u}). FIXED-C softmax (see R6 comment).
// R10: Ps[wave][2] (48KB LDS -> 3 blocks/CU by LDS limit) with
// launch_bounds(256,2): the (256,3) bound capped unified VGPR+AGPR at ~170
// and forced scratch spill (R8/R9: VGPR squeezed to 84, 85-274MB scratch
// traffic). (256,2) gives the allocator room (R7: 108 VGPR, no spill);
// occupancy is then LDS-limited at 3 blocks/CU.
__global__ __launch_bounds__(256, 2) void attn_fwd(const u16* __restrict__ Qn,
                                                   const u16* __restrict__ Kn,
                                                   const u16* __restrict__ Vt,
                                                   u16* __restrict__ Aout) {
  __shared__ u16 Ks[2][64 * 64];
  __shared__ u16 Vs[2][64 * 64];
  __shared__ u16 Ps[4][2][1024];  // [wave][half-frag][16 q-rows x 64 kv]
  const int bid = blockIdx.x;     // B_*KVH_*32
  const int u = bid & 31;
  const int kvh = (bid >> 5) & 7;
  const int b = bid >> 8;
  const int q0A = u << 5;
  const int q0B = (63 - u) << 5;
  const int JT_A = (u >> 1) + 1;
  const int JT_B = 32 - (u >> 1);
  const int tid = threadIdx.x;
  const int lane = tid & 63;
  const int wave = tid >> 6;
  const int h = kvh * 4 + wave;  // this wave's Q head
  const int ql = lane & 15;
  const int g = lane >> 4;
  const float SCL2E = 0.125f * 1.44269504088896340736f;

  // Q frags: ff=0,1 -> tile A rows q0A+16*ff+ql; ff=2,3 -> tile B
  short8 qa[4][2];
  int rowq[4];
#pragma unroll
  for (int ff = 0; ff < 4; ff++) {
    const int q0 = (ff < 2) ? q0A : q0B;
    rowq[ff] = q0 + 16 * (ff & 1) + ql;
    const u16* qb = Qn + (((size_t)(b * H_ + h)) * S_ + rowq[ff]) * HD_;
    qa[ff][0] = *reinterpret_cast<const short8*>(qb + g * 8);
    qa[ff][1] = *reinterpret_cast<const short8*>(qb + 32 + g * 8);
  }

  const f32x4 zero4 = {0.f, 0.f, 0.f, 0.f};
  f32x4 oacc[4][4];  // [dn][ff]
#pragma unroll
  for (int dn = 0; dn < 4; dn++)
#pragma unroll
    for (int ff = 0; ff < 4; ff++) oacc[dn][ff] = zero4;
  float psum[4] = {0.f, 0.f, 0.f, 0.f};

  const u16* kg = Kn + ((size_t)(b * KVH_ + kvh)) * S_ * HD_;
  const u16* vg = Vt + ((size_t)(b * KVH_ + kvh)) * HD_ * S_;

  const int c0 = tid, c1 = 256 + tid;
  const int r0 = c0 >> 3, sl0 = (c0 & 7) ^ (r0 & 7);
  const int r1 = c1 >> 3, sl1 = (c1 & 7) ^ (r1 & 7);
  const int xsw2 = (ql & 7) << 2;

  auto stage = [&](int jt, int buf) {
    const int j0 = jt << 6;
    GLDS16(kg + (size_t)(j0 + r0) * HD_ + sl0 * 8, Ks[buf] + c0 * 8);
    GLDS16(kg + (size_t)(j0 + r1) * HD_ + sl1 * 8, Ks[buf] + c1 * 8);
    GLDS16(vg + (size_t)r0 * S_ + j0 + sl0 * 8, Vs[buf] + c0 * 8);
    GLDS16(vg + (size_t)r1 * S_ + j0 + sl1 * 8, Vs[buf] + c1 * 8);
  };

  stage(0, 0);
  __syncthreads();  // drain prologue stage
  int cur = 0;
  for (int jt = 0; jt < JT_B; jt++) {
    if (jt + 1 < JT_B) stage(jt + 1, cur ^ 1);  // issue next tile early
    const int j0 = jt << 6;
    const u16* ksb = Ks[cur];
    const u16* vsb = Vs[cur];
    const bool actA = (jt < JT_A);

    short8 pa[4][2];
    // per q-tile pair: S^T = K·Q^T, then p = exp2(fma(s,SCL2E,-12)), pack->LDS,
    // read back B-frags (wave-private buffer, DS ops in-order per wave)
#pragma unroll
    for (int p = 0; p < 2; p++) {
      if (p == 0 && !actA) continue;
      f32x4 sc[4][2];
#pragma unroll
      for (int n = 0; n < 4; n++)
#pragma unroll
        for (int f = 0; f < 2; f++) sc[n][f] = zero4;
      __builtin_amdgcn_s_setprio(1);
#pragma unroll
      for (int ks = 0; ks < 2; ks++) {
        const int sd = ks * 4 + g;
#pragma unroll
        for (int n = 0; n < 4; n++) {
          const int r = n * 16 + ql;
          short8 kf = *reinterpret_cast<const short8*>(ksb + r * 64 + ((sd ^ (r & 7)) << 3));
          sc[n][0] = __builtin_amdgcn_mfma_f32_16x16x32_bf16(kf, qa[2 * p][ks], sc[n][0], 0, 0, 0);
          sc[n][1] = __builtin_amdgcn_mfma_f32_16x16x32_bf16(kf, qa[2 * p + 1][ks], sc[n][1], 0, 0, 0);
        }
      }
      __builtin_amdgcn_s_setprio(0);
#pragma unroll
      for (int f = 0; f < 2; f++) {
        const int ff = 2 * p + f;
        const int jtEnd = (p == 0) ? JT_A : JT_B;
        const bool diag = (jt == jtEnd - 1);
        float pv[4][4];
#pragma unroll
        for (int n = 0; n < 4; n++)
#pragma unroll
          for (int r = 0; r < 4; r++)
            pv[n][r] = exp2f(fmaf(sc[n][f][r], SCL2E, -12.0f));
        if (diag) {
#pragma unroll
          for (int n = 0; n < 4; n++)
#pragma unroll
            for (int r = 0; r < 4; r++)
              if ((j0 + n * 16 + 4 * g + r) > rowq[ff]) pv[n][r] = 0.f;
        }
        u32* pw32 = reinterpret_cast<u32*>(Ps[wave][f]);
#pragma unroll
        for (int n = 0; n < 4; n++) {
          psum[ff] += (pv[n][0] + pv[n][1]) + (pv[n][2] + pv[n][3]);
          union { u32 w; u16 hh[2]; } c01, c23;
          c01.hh[0] = f2bf(pv[n][0]); c01.hh[1] = f2bf(pv[n][1]);
          c23.hh[0] = f2bf(pv[n][2]); c23.hh[1] = f2bf(pv[n][3]);
          const int idx = ql * 32 + (((n << 3) + (g << 1)) ^ xsw2);
          pw32[idx] = c01.w;
          pw32[idx + 1] = c23.w;
        }
      }
#pragma unroll
      for (int f = 0; f < 2; f++)
#pragma unroll
        for (int ks = 0; ks < 2; ks++)
          pa[2 * p + f][ks] = *reinterpret_cast<const short8*>(
              Ps[wave][f] + ql * 64 + ((32 * ks + 8 * g) ^ (xsw2 << 1)));
    }

    // O^T += V^T · P^T (vf shared across frags)
    __builtin_amdgcn_s_setprio(1);
#pragma unroll
    for (int ks = 0; ks < 2; ks++) {
      const int sd = ks * 4 + g;
#pragma unroll
      for (int dn = 0; dn < 4; dn++) {
        const int vr = dn * 16 + ql;
        short8 vf = *reinterpret_cast<const short8*>(vsb + vr * 64 + ((sd ^ (vr & 7)) << 3));
        if (actA) {
          oacc[dn][0] = __builtin_amdgcn_mfma_f32_16x16x32_bf16(vf, pa[0][ks], oacc[dn][0], 0, 0, 0);
          oacc[dn][1] = __builtin_amdgcn_mfma_f32_16x16x32_bf16(vf, pa[1][ks], oacc[dn][1], 0, 0, 0);
        }
        oacc[dn][2] = __builtin_amdgcn_mfma_f32_16x16x32_bf16(vf, pa[2][ks], oacc[dn][2], 0, 0, 0);
        oacc[dn][3] = __builtin_amdgcn_mfma_f32_16x16x32_bf16(vf, pa[3][ks], oacc[dn][3], 0, 0, 0);
      }
    }
    __builtin_amdgcn_s_setprio(0);

    __syncthreads();  // stage(jt+1) drained + all reads of buf[cur] done
    cur ^= 1;
  }

  // final denominator reduce (once) + output
#pragma unroll
  for (int ff = 0; ff < 4; ff++) {
    float s = psum[ff];
    s += __shfl_xor(s, 16);
    s += __shfl_xor(s, 32);
    const float il = 1.0f / s;
#pragma unroll
    for (int dn = 0; dn < 4; dn++) {
      union { short4v v; u16 uu[4]; } o;
#pragma unroll
      for (int r = 0; r < 4; r++) o.uu[r] = f2bf(oacc[dn][ff][r] * il);
      u16* dst = Aout + ((size_t)b * S_ + rowq[ff]) * D_ + h * HD_ + dn * 16 + 4 * g;
      *reinterpret_cast<short4v*>(dst) = o.v;
    }
  }
}

// ---------------- launcher ----------------
extern "C" void kernel_launch(void* const* d_in, const int* in_sizes, int n_in,
                              void* d_out, int out_size, void* d_ws,
                              size_t ws_size, hipStream_t stream) {
  const float* x = (const float*)d_in[0];
  const float* wqkv = (const float*)d_in[1];
  const float* wout = (const float*)d_in[2];
  const float* gain = (const float*)d_in[3];

  float* out_attn = (float*)d_out;                       // (B,S,D) f32
  float* out_vflat = out_attn + (size_t)B_ * S_ * D_;    // (H*B,S,HD) f32

  uint8_t* w = (uint8_t*)d_ws;
  u16* xb     = (u16*)(w);                      // 16,777,216 B
  u16* wqkvb  = (u16*)(w + 16777216);           // 12,582,912 B
  u16* woutb  = (u16*)(w + 29360128);           //  8,388,608 B
  float* proj = (float*)(w + 37748736);         // 50,331,648 B
  u16* Qn     = (u16*)(w + 88080384);           // 16,777,216 B
  u16* Kn     = (u16*)(w + 104857600);          //  4,194,304 B
  u16* Vt     = (u16*)(w + 109051904);          //  4,194,304 B
  u16* attnb  = (u16*)(w + 113246208);          // 16,777,216 B
  float* tc   = (float*)(w + 130023424);        //    262,144 B
  float* ts   = (float*)(w + 130285568);        //    262,144 B
  // total: 130,547,712 B

  pack_bf16<<<4096, 256, 0, stream>>>(x, xb, B_ * S_ * D_);
  pack_bf16<<<3072, 256, 0, stream>>>(wqkv, wqkvb, PROJN * D_);
  pack_bf16<<<2048, 256, 0, stream>>>(wout, woutb, D_ * D_);
  rope_table<<<256, 256, 0, stream>>>(tc, ts);

  // proj = x @ w_qkv^T : (4096 x 3072)
  gemm_bt<<<(4096 / 128) * (3072 / 128), 256, 0, stream>>>(xb, wqkvb, proj,
                                                           4096, PROJN, 2048);
  rope_norm<<<(B_ * S_ * 40) / 4, 256, 0, stream>>>(proj, tc, ts, gain, Qn, Kn);
  vtrans<<<B_ * KVH_ * (S_ / 64), 256, 0, stream>>>(proj, Vt, out_vflat);
  // one block per q-tile PAIR: B_*KVH_*32 blocks
  attn_fwd<<<B_ * KVH_ * (S_ / 64), 256, 0, stream>>>(Qn, Kn, Vt, attnb);
  // attn_out = attn @ w_out^T : (4096 x 2048)
  gemm_bt<<<(4096 / 128) * (2048 / 128), 256, 0, stream>>>(attnb, woutb,
                                                           out_attn, 4096,
                                                           2048, 2048);
}

// Round 11
// 244.336 us; speedup vs baseline: 1.3033x; 1.0341x over previous
//
#include <hip/hip_runtime.h>
#include <hip/hip_bf16.h>
#include <cstdint>
#include <cstddef>

#define B_ 2
#define S_ 2048
#define D_ 2048
#define H_ 32
#define KVH_ 8
#define HD_ 64
#define PROJN 3072   // Q_OUT(2048) + 2*KV_OUT(512)

typedef unsigned short u16;
typedef unsigned int u32;
typedef __attribute__((ext_vector_type(8))) short short8;
typedef __attribute__((ext_vector_type(4))) short short4v;
typedef __attribute__((ext_vector_type(4))) float f32x4;

__device__ __forceinline__ u16 f2bf(float f) {
  __hip_bfloat16 h = __float2bfloat16(f);
  return *reinterpret_cast<u16*>(&h);
}

#define GLDS16(g, l)                                                           \
  __builtin_amdgcn_global_load_lds(                                            \
      (const __attribute__((address_space(1))) void*)(g),                      \
      (__attribute__((address_space(3))) void*)(l), 16, 0, 0)

// ---------------- pack f32 -> bf16 ----------------
__global__ __launch_bounds__(256) void pack_bf16(const float* __restrict__ in,
                                                 u16* __restrict__ out, int n) {
  int i = (blockIdx.x * 256 + threadIdx.x) * 8;
  if (i >= n) return;
  const float4* p = reinterpret_cast<const float4*>(in + i);
  float4 a = p[0], b = p[1];
  union { short8 v; u16 u[8]; } r;
  r.u[0] = f2bf(a.x); r.u[1] = f2bf(a.y); r.u[2] = f2bf(a.z); r.u[3] = f2bf(a.w);
  r.u[4] = f2bf(b.x); r.u[5] = f2bf(b.y); r.u[6] = f2bf(b.z); r.u[7] = f2bf(b.w);
  *reinterpret_cast<short8*>(out + i) = r.v;
}

// ---------------- rope cos/sin table ----------------
__global__ __launch_bounds__(256) void rope_table(float* __restrict__ tc,
                                                  float* __restrict__ ts) {
  int i = blockIdx.x * 256 + threadIdx.x;  // S_*32
  int s = i >> 5, j = i & 31;
  float e = (float)(2 * j) / 64.0f;
  float inv_freq = 1.0f / powf(10000.0f, e);
  float ang = (float)s * inv_freq;
  tc[i] = cosf(ang);
  ts[i] = sinf(ang);
}

// ---------------- bf16 GEMM: C[M,N] = A[M,K] * Bw[N,K]^T ----------------
__global__ __launch_bounds__(256) void gemm_bt(const u16* __restrict__ A,
                                               const u16* __restrict__ Bw,
                                               float* __restrict__ C, int M,
                                               int N, int K) {
  __shared__ u16 As[128 * 64];
  __shared__ u16 Bs[128 * 64];
  const int tid = threadIdx.x;
  const int lane = tid & 63;
  const int wave = tid >> 6;
  const int ntile = N >> 7;
  const int m0 = (blockIdx.x / ntile) << 7;
  const int n0 = (blockIdx.x % ntile) << 7;
  const int wr = (wave >> 1) << 6;
  const int wc = (wave & 1) << 6;
  const int arow = lane & 15;
  const int kgrp = lane >> 4;

  const f32x4 zero4 = {0.f, 0.f, 0.f, 0.f};
  f32x4 acc[4][4];
#pragma unroll
  for (int m = 0; m < 4; m++)
#pragma unroll
    for (int n = 0; n < 4; n++) acc[m][n] = zero4;

  int srow[4], sslot[4];
#pragma unroll
  for (int i = 0; i < 4; i++) {
    int c = i * 256 + tid;
    srow[i] = c >> 3;
    sslot[i] = (c & 7) ^ (srow[i] & 7);  // inverse-swizzled source slot
  }

  auto stage = [&](int kt) {
    const int k0 = kt << 6;
#pragma unroll
    for (int i = 0; i < 4; i++) {
      const u16* ga = A + (size_t)(m0 + srow[i]) * K + k0 + sslot[i] * 8;
      GLDS16(ga, As + (i * 256 + tid) * 8);
    }
#pragma unroll
    for (int i = 0; i < 4; i++) {
      const u16* gb = Bw + (size_t)(n0 + srow[i]) * K + k0 + sslot[i] * 8;
      GLDS16(gb, Bs + (i * 256 + tid) * 8);
    }
  };

  const int KT = K >> 6;
  stage(0);
  for (int kt = 0;; kt++) {
    __syncthreads();  // staging drained (compiler emits vmcnt(0) before barrier)
#pragma unroll
    for (int ks = 0; ks < 2; ks++) {
      const int sd = ks * 4 + kgrp;
      short8 a[4], b[4];
#pragma unroll
      for (int m = 0; m < 4; m++) {
        int r = wr + m * 16 + arow;
        a[m] = *reinterpret_cast<const short8*>(As + r * 64 + ((sd ^ (r & 7)) << 3));
      }
#pragma unroll
      for (int n = 0; n < 4; n++) {
        int r = wc + n * 16 + arow;
        b[n] = *reinterpret_cast<const short8*>(Bs + r * 64 + ((sd ^ (r & 7)) << 3));
      }
#pragma unroll
      for (int m = 0; m < 4; m++)
#pragma unroll
        for (int n = 0; n < 4; n++)
          acc[m][n] = __builtin_amdgcn_mfma_f32_16x16x32_bf16(a[m], b[n], acc[m][n], 0, 0, 0);
    }
    if (kt + 1 == KT) break;
    __syncthreads();
    stage(kt + 1);
  }

  const int crow = kgrp * 4;
#pragma unroll
  for (int m = 0; m < 4; m++) {
#pragma unroll
    for (int n = 0; n < 4; n++) {
      float* cp = C + (size_t)(m0 + wr + m * 16 + crow) * N + n0 + wc + n * 16 + arow;
#pragma unroll
      for (int r = 0; r < 4; r++) cp[(size_t)r * N] = acc[m][n][r];
    }
  }
}

// ---------------- RoPE + RMSNorm for Q and K ----------------
// one wave per (b, s, head'), head' in [0,40): 0..31 Q heads, 32..39 K heads
__global__ __launch_bounds__(256) void rope_norm(
    const float* __restrict__ proj, const float* __restrict__ tc,
    const float* __restrict__ ts, const float* __restrict__ gain,
    u16* __restrict__ Qn, u16* __restrict__ Kn) {
  int wid = (blockIdx.x * 256 + threadIdx.x) >> 6;  // B_*S_*40 waves
  int lane = threadIdx.x & 63;
  int hh = wid % 40;
  int bs = wid / 40;  // b*S_ + s
  int s = bs & (S_ - 1);
  int b = bs >> 11;
  int off = hh < 32 ? hh * 64 + lane : 2048 + (hh - 32) * 64 + lane;
  float val = proj[(size_t)bs * PROJN + off];
  int j = lane & 31;
  float c = tc[s * 32 + j], sn = ts[s * 32 + j];
  float partner = __shfl_xor(val, 32);
  float out = lane < 32 ? val * c - partner * sn : val * c + partner * sn;
  float ss = out * out;
#pragma unroll
  for (int m = 32; m >= 1; m >>= 1) ss += __shfl_xor(ss, m);
  float inv = rsqrtf(ss * (1.0f / 64.0f) + 1e-6f);
  float g = hh < 32 ? gain[0] : 1.0f;
  u16 ub = f2bf(out * inv * g);
  if (hh < 32)
    Qn[(((size_t)(b * H_ + hh)) * S_ + s) * HD_ + lane] = ub;
  else
    Kn[(((size_t)(b * KVH_ + (hh - 32))) * S_ + s) * HD_ + lane] = ub;
}

// ---------------- V: transpose to (B,KVH,HD,S) bf16 + V_flat f32 output ----------------
__global__ __launch_bounds__(256) void vtrans(const float* __restrict__ proj,
                                              u16* __restrict__ Vt,
                                              float* __restrict__ Vout) {
  __shared__ float tile[64][65];
  const int bid = blockIdx.x;  // B_*KVH_*(S_/64)
  const int st = bid & 31;
  const int s0 = st << 6;
  const int kvh = (bid >> 5) & 7;
  const int b = bid >> 8;
  const int t = threadIdx.x;
  const int sr = t >> 2;
  const int d0 = (t & 3) << 4;
  const float* src = proj + ((size_t)(b * S_ + s0 + sr)) * PROJN + 2560 + kvh * 64 + d0;
  float v[16];
#pragma unroll
  for (int i = 0; i < 16; i += 4) {
    float4 x = *reinterpret_cast<const float4*>(src + i);
    v[i] = x.x; v[i + 1] = x.y; v[i + 2] = x.z; v[i + 3] = x.w;
  }
  // V_flat output: rows h*B+b, 4 repeated heads (scale rsqrt(1+1e-8) == 1.0f exactly)
#pragma unroll
  for (int hh = 0; hh < 4; hh++) {
    int hq = kvh * 4 + hh;
    float* dst = Vout + (((size_t)(hq * B_ + b)) * S_ + s0 + sr) * HD_ + d0;
#pragma unroll
    for (int i = 0; i < 16; i += 4)
      *reinterpret_cast<float4*>(dst + i) = make_float4(v[i], v[i + 1], v[i + 2], v[i + 3]);
  }
#pragma unroll
  for (int i = 0; i < 16; i++) tile[sr][d0 + i] = v[i];
  __syncthreads();
  const int d = t >> 2;
  const int sc = (t & 3) << 4;
  union { short8 v8; u16 u[8]; } o0, o1;
#pragma unroll
  for (int i = 0; i < 8; i++) o0.u[i] = f2bf(tile[sc + i][d]);
#pragma unroll
  for (int i = 0; i < 8; i++) o1.u[i] = f2bf(tile[sc + 8 + i][d]);
  u16* dst = Vt + (((size_t)(b * KVH_ + kvh)) * HD_ + d) * S_ + s0 + sc;
  *reinterpret_cast<short8*>(dst) = o0.v8;
  *reinterpret_cast<short8*>(dst + 8) = o1.v8;
}

// ---------------- flash attention (causal, GQA) ----------------
// R11: UNPAIRED q-tiles — 1024 blocks, one 32-row q-tile each, LPT dispatch
// order (bid = i*16 + group, qt = 63-i: longest blocks launch first).
// LDS 40KB (K/V dbuf 32KB + single Ps 8KB reused per frag; wave-private,
// DS in-order) -> 4 blocks/CU. FIXED-C softmax (see R6). launch_bounds(256,2)
// (the (256,3) cap caused scratch spill, R8-R10 lesson).
__global__ __launch_bounds__(256, 2) void attn_fwd(const u16* __restrict__ Qn,
                                                   const u16* __restrict__ Kn,
                                                   const u16* __restrict__ Vt,
                                                   u16* __restrict__ Aout) {
  __shared__ u16 Ks[2][64 * 64];
  __shared__ u16 Vs[2][64 * 64];
  __shared__ u16 Ps[4][1024];  // [wave][16 q-rows x 64 kv], reused per frag
  const int bid = blockIdx.x;  // 64 tile-slots x 16 groups
  const int grp = bid & 15;    // (b,kvh)
  const int i = bid >> 4;      // 0..63, i=0 -> longest tile (LPT)
  const int qt = 63 - i;
  const int b = grp >> 3;
  const int kvh = grp & 7;
  const int q0 = qt << 5;
  const int JT = (qt >> 1) + 1;
  const int tid = threadIdx.x;
  const int lane = tid & 63;
  const int wave = tid >> 6;
  const int h = kvh * 4 + wave;  // this wave's Q head
  const int ql = lane & 15;
  const int g = lane >> 4;
  const float SCL2E = 0.125f * 1.44269504088896340736f;

  // Q frags: f=0,1 -> rows q0+16*f+ql
  short8 qa[2][2];
  int rowq[2];
#pragma unroll
  for (int f = 0; f < 2; f++) {
    rowq[f] = q0 + 16 * f + ql;
    const u16* qb = Qn + (((size_t)(b * H_ + h)) * S_ + rowq[f]) * HD_;
    qa[f][0] = *reinterpret_cast<const short8*>(qb + g * 8);
    qa[f][1] = *reinterpret_cast<const short8*>(qb + 32 + g * 8);
  }

  const f32x4 zero4 = {0.f, 0.f, 0.f, 0.f};
  f32x4 oacc[4][2];  // [dn][f]
#pragma unroll
  for (int dn = 0; dn < 4; dn++)
#pragma unroll
    for (int f = 0; f < 2; f++) oacc[dn][f] = zero4;
  float psum[2] = {0.f, 0.f};

  const u16* kg = Kn + ((size_t)(b * KVH_ + kvh)) * S_ * HD_;
  const u16* vg = Vt + ((size_t)(b * KVH_ + kvh)) * HD_ * S_;

  const int c0 = tid, c1 = 256 + tid;
  const int r0 = c0 >> 3, sl0 = (c0 & 7) ^ (r0 & 7);
  const int r1 = c1 >> 3, sl1 = (c1 & 7) ^ (r1 & 7);
  const int xsw2 = (ql & 7) << 2;

  auto stage = [&](int jt, int buf) {
    const int j0 = jt << 6;
    GLDS16(kg + (size_t)(j0 + r0) * HD_ + sl0 * 8, Ks[buf] + c0 * 8);
    GLDS16(kg + (size_t)(j0 + r1) * HD_ + sl1 * 8, Ks[buf] + c1 * 8);
    GLDS16(vg + (size_t)r0 * S_ + j0 + sl0 * 8, Vs[buf] + c0 * 8);
    GLDS16(vg + (size_t)r1 * S_ + j0 + sl1 * 8, Vs[buf] + c1 * 8);
  };

  stage(0, 0);
  __syncthreads();  // drain prologue stage
  int cur = 0;
  for (int jt = 0; jt < JT; jt++) {
    if (jt + 1 < JT) stage(jt + 1, cur ^ 1);  // issue next tile early
    const int j0 = jt << 6;
    const u16* ksb = Ks[cur];
    const u16* vsb = Vs[cur];
    const bool diag = (jt == JT - 1);

    // S^T = K·Q^T for both frags (kf shared)
    f32x4 sc[4][2];
#pragma unroll
    for (int n = 0; n < 4; n++)
#pragma unroll
      for (int f = 0; f < 2; f++) sc[n][f] = zero4;
    __builtin_amdgcn_s_setprio(1);
#pragma unroll
    for (int ks = 0; ks < 2; ks++) {
      const int sd = ks * 4 + g;
#pragma unroll
      for (int n = 0; n < 4; n++) {
        const int r = n * 16 + ql;
        short8 kf = *reinterpret_cast<const short8*>(ksb + r * 64 + ((sd ^ (r & 7)) << 3));
        sc[n][0] = __builtin_amdgcn_mfma_f32_16x16x32_bf16(kf, qa[0][ks], sc[n][0], 0, 0, 0);
        sc[n][1] = __builtin_amdgcn_mfma_f32_16x16x32_bf16(kf, qa[1][ks], sc[n][1], 0, 0, 0);
      }
    }
    __builtin_amdgcn_s_setprio(0);

    // exp2 + mask + pack -> Ps (single buffer, reused per frag; DS in-order)
    short8 pa[2][2];
#pragma unroll
    for (int f = 0; f < 2; f++) {
      float pv[4][4];
#pragma unroll
      for (int n = 0; n < 4; n++)
#pragma unroll
        for (int r = 0; r < 4; r++)
          pv[n][r] = exp2f(fmaf(sc[n][f][r], SCL2E, -12.0f));
      if (diag) {
#pragma unroll
        for (int n = 0; n < 4; n++)
#pragma unroll
          for (int r = 0; r < 4; r++)
            if ((j0 + n * 16 + 4 * g + r) > rowq[f]) pv[n][r] = 0.f;
      }
      u32* pw32 = reinterpret_cast<u32*>(Ps[wave]);
#pragma unroll
      for (int n = 0; n < 4; n++) {
        psum[f] += (pv[n][0] + pv[n][1]) + (pv[n][2] + pv[n][3]);
        union { u32 w; u16 hh[2]; } c01, c23;
        c01.hh[0] = f2bf(pv[n][0]); c01.hh[1] = f2bf(pv[n][1]);
        c23.hh[0] = f2bf(pv[n][2]); c23.hh[1] = f2bf(pv[n][3]);
        const int idx = ql * 32 + (((n << 3) + (g << 1)) ^ xsw2);
        pw32[idx] = c01.w;
        pw32[idx + 1] = c23.w;
      }
#pragma unroll
      for (int ks = 0; ks < 2; ks++)
        pa[f][ks] = *reinterpret_cast<const short8*>(
            Ps[wave] + ql * 64 + ((32 * ks + 8 * g) ^ (xsw2 << 1)));
    }

    // O^T += V^T · P^T (vf shared across frags)
    __builtin_amdgcn_s_setprio(1);
#pragma unroll
    for (int ks = 0; ks < 2; ks++) {
      const int sd = ks * 4 + g;
#pragma unroll
      for (int dn = 0; dn < 4; dn++) {
        const int vr = dn * 16 + ql;
        short8 vf = *reinterpret_cast<const short8*>(vsb + vr * 64 + ((sd ^ (vr & 7)) << 3));
        oacc[dn][0] = __builtin_amdgcn_mfma_f32_16x16x32_bf16(vf, pa[0][ks], oacc[dn][0], 0, 0, 0);
        oacc[dn][1] = __builtin_amdgcn_mfma_f32_16x16x32_bf16(vf, pa[1][ks], oacc[dn][1], 0, 0, 0);
      }
    }
    __builtin_amdgcn_s_setprio(0);

    __syncthreads();  // stage(jt+1) drained + all reads of buf[cur] done
    cur ^= 1;
  }

  // final denominator reduce (once) + output
#pragma unroll
  for (int f = 0; f < 2; f++) {
    float s = psum[f];
    s += __shfl_xor(s, 16);
    s += __shfl_xor(s, 32);
    const float il = 1.0f / s;
#pragma unroll
    for (int dn = 0; dn < 4; dn++) {
      union { short4v v; u16 uu[4]; } o;
#pragma unroll
      for (int r = 0; r < 4; r++) o.uu[r] = f2bf(oacc[dn][f][r] * il);
      u16* dst = Aout + ((size_t)b * S_ + rowq[f]) * D_ + h * HD_ + dn * 16 + 4 * g;
      *reinterpret_cast<short4v*>(dst) = o.v;
    }
  }
}

// ---------------- launcher ----------------
extern "C" void kernel_launch(void* const* d_in, const int* in_sizes, int n_in,
                              void* d_out, int out_size, void* d_ws,
                              size_t ws_size, hipStream_t stream) {
  const float* x = (const float*)d_in[0];
  const float* wqkv = (const float*)d_in[1];
  const float* wout = (const float*)d_in[2];
  const float* gain = (const float*)d_in[3];

  float* out_attn = (float*)d_out;                       // (B,S,D) f32
  float* out_vflat = out_attn + (size_t)B_ * S_ * D_;    // (H*B,S,HD) f32

  uint8_t* w = (uint8_t*)d_ws;
  u16* xb     = (u16*)(w);                      // 16,777,216 B
  u16* wqkvb  = (u16*)(w + 16777216);           // 12,582,912 B
  u16* woutb  = (u16*)(w + 29360128);           //  8,388,608 B
  float* proj = (float*)(w + 37748736);         // 50,331,648 B
  u16* Qn     = (u16*)(w + 88080384);           // 16,777,216 B
  u16* Kn     = (u16*)(w + 104857600);          //  4,194,304 B
  u16* Vt     = (u16*)(w + 109051904);          //  4,194,304 B
  u16* attnb  = (u16*)(w + 113246208);          // 16,777,216 B
  float* tc   = (float*)(w + 130023424);        //    262,144 B
  float* ts   = (float*)(w + 130285568);        //    262,144 B
  // total: 130,547,712 B

  pack_bf16<<<4096, 256, 0, stream>>>(x, xb, B_ * S_ * D_);
  pack_bf16<<<3072, 256, 0, stream>>>(wqkv, wqkvb, PROJN * D_);
  pack_bf16<<<2048, 256, 0, stream>>>(woutb ? wout : wout, woutb, D_ * D_);
  rope_table<<<256, 256, 0, stream>>>(tc, ts);

  // proj = x @ w_qkv^T : (4096 x 3072)
  gemm_bt<<<(4096 / 128) * (3072 / 128), 256, 0, stream>>>(xb, wqkvb, proj,
                                                           4096, PROJN, 2048);
  rope_norm<<<(B_ * S_ * 40) / 4, 256, 0, stream>>>(proj, tc, ts, gain, Qn, Kn);
  vtrans<<<B_ * KVH_ * (S_ / 64), 256, 0, stream>>>(proj, Vt, out_vflat);
  // 1024 blocks: one 32-row q-tile each, LPT-ordered (longest first)
  attn_fwd<<<B_ * KVH_ * (S_ / 32), 256, 0, stream>>>(Qn, Kn, Vt, attnb);
  // attn_out = attn @ w_out^T : (4096 x 2048)
  gemm_bt<<<(4096 / 128) * (2048 / 128), 256, 0, stream>>>(attnb, woutb,
                                                           out_attn, 4096,
                                                           2048, 2048);
}

// Round 12
// 239.389 us; speedup vs baseline: 1.3302x; 1.0207x over previous
//
#include <hip/hip_runtime.h>
#include <hip/hip_bf16.h>
#include <cstdint>
#include <cstddef>

#define B_ 2
#define S_ 2048
#define D_ 2048
#define H_ 32
#define KVH_ 8
#define HD_ 64
#define PROJN 3072   // Q_OUT(2048) + 2*KV_OUT(512)

typedef unsigned short u16;
typedef unsigned int u32;
typedef __attribute__((ext_vector_type(8))) short short8;
typedef __attribute__((ext_vector_type(4))) short short4v;
typedef __attribute__((ext_vector_type(4))) float f32x4;

__device__ __forceinline__ u16 f2bf(float f) {
  __hip_bfloat16 h = __float2bfloat16(f);
  return *reinterpret_cast<u16*>(&h);
}

#define GLDS16(g, l)                                                           \
  __builtin_amdgcn_global_load_lds(                                            \
      (const __attribute__((address_space(1))) void*)(g),                      \
      (__attribute__((address_space(3))) void*)(l), 16, 0, 0)

// ---------------- pack f32 -> bf16 ----------------
__global__ __launch_bounds__(256) void pack_bf16(const float* __restrict__ in,
                                                 u16* __restrict__ out, int n) {
  int i = (blockIdx.x * 256 + threadIdx.x) * 8;
  if (i >= n) return;
  const float4* p = reinterpret_cast<const float4*>(in + i);
  float4 a = p[0], b = p[1];
  union { short8 v; u16 u[8]; } r;
  r.u[0] = f2bf(a.x); r.u[1] = f2bf(a.y); r.u[2] = f2bf(a.z); r.u[3] = f2bf(a.w);
  r.u[4] = f2bf(b.x); r.u[5] = f2bf(b.y); r.u[6] = f2bf(b.z); r.u[7] = f2bf(b.w);
  *reinterpret_cast<short8*>(out + i) = r.v;
}

// ---------------- transposed rope tables: tct/tst[j][s], j<32, s<2048 ----------------
__global__ __launch_bounds__(256) void rope_tabT(float* __restrict__ tct,
                                                 float* __restrict__ tst) {
  int i = blockIdx.x * 256 + threadIdx.x;  // 32*2048
  int j = i >> 11, s = i & 2047;
  float e = (float)(2 * j) / 64.0f;
  float inv_freq = 1.0f / powf(10000.0f, e);
  float ang = (float)s * inv_freq;
  tct[i] = cosf(ang);
  tst[i] = sinf(ang);
}

// ---------------- bf16 GEMM: C[M,N] = A[M,K] * Bw[N,K]^T (f32 out) ----------------
__global__ __launch_bounds__(256) void gemm_bt(const u16* __restrict__ A,
                                               const u16* __restrict__ Bw,
                                               float* __restrict__ C, int M,
                                               int N, int K) {
  __shared__ u16 As[128 * 64];
  __shared__ u16 Bs[128 * 64];
  const int tid = threadIdx.x;
  const int lane = tid & 63;
  const int wave = tid >> 6;
  const int ntile = N >> 7;
  const int m0 = (blockIdx.x / ntile) << 7;
  const int n0 = (blockIdx.x % ntile) << 7;
  const int wr = (wave >> 1) << 6;
  const int wc = (wave & 1) << 6;
  const int arow = lane & 15;
  const int kgrp = lane >> 4;

  const f32x4 zero4 = {0.f, 0.f, 0.f, 0.f};
  f32x4 acc[4][4];
#pragma unroll
  for (int m = 0; m < 4; m++)
#pragma unroll
    for (int n = 0; n < 4; n++) acc[m][n] = zero4;

  int srow[4], sslot[4];
#pragma unroll
  for (int i = 0; i < 4; i++) {
    int c = i * 256 + tid;
    srow[i] = c >> 3;
    sslot[i] = (c & 7) ^ (srow[i] & 7);
  }

  auto stage = [&](int kt) {
    const int k0 = kt << 6;
#pragma unroll
    for (int i = 0; i < 4; i++) {
      const u16* ga = A + (size_t)(m0 + srow[i]) * K + k0 + sslot[i] * 8;
      GLDS16(ga, As + (i * 256 + tid) * 8);
    }
#pragma unroll
    for (int i = 0; i < 4; i++) {
      const u16* gb = Bw + (size_t)(n0 + srow[i]) * K + k0 + sslot[i] * 8;
      GLDS16(gb, Bs + (i * 256 + tid) * 8);
    }
  };

  const int KT = K >> 6;
  stage(0);
  for (int kt = 0;; kt++) {
    __syncthreads();
#pragma unroll
    for (int ks = 0; ks < 2; ks++) {
      const int sd = ks * 4 + kgrp;
      short8 a[4], b[4];
#pragma unroll
      for (int m = 0; m < 4; m++) {
        int r = wr + m * 16 + arow;
        a[m] = *reinterpret_cast<const short8*>(As + r * 64 + ((sd ^ (r & 7)) << 3));
      }
#pragma unroll
      for (int n = 0; n < 4; n++) {
        int r = wc + n * 16 + arow;
        b[n] = *reinterpret_cast<const short8*>(Bs + r * 64 + ((sd ^ (r & 7)) << 3));
      }
#pragma unroll
      for (int m = 0; m < 4; m++)
#pragma unroll
        for (int n = 0; n < 4; n++)
          acc[m][n] = __builtin_amdgcn_mfma_f32_16x16x32_bf16(a[m], b[n], acc[m][n], 0, 0, 0);
    }
    if (kt + 1 == KT) break;
    __syncthreads();
    stage(kt + 1);
  }

  const int crow = kgrp * 4;
#pragma unroll
  for (int m = 0; m < 4; m++) {
#pragma unroll
    for (int n = 0; n < 4; n++) {
      float* cp = C + (size_t)(m0 + wr + m * 16 + crow) * N + n0 + wc + n * 16 + arow;
#pragma unroll
      for (int r = 0; r < 4; r++) cp[(size_t)r * N] = acc[m][n][r];
    }
  }
}

// ---------------- fused QKV GEMM: proj + RoPE + RMSNorm + pack ----------------
// M=4096, N=3072, K=2048. Each wave's 64-col slice = exactly one head.
// hslice<32: Q head (rope+norm, scale gain*SCL2E, bf16 -> Qn)
// 32..39:    K head (rope+norm, bf16 -> Kn)
// 40..47:    V head (raw f32 -> projV, consumed by vtrans)
// RoPE pair (d, d+32) = (acc[m][n], acc[m][n+2]) — register-local.
__global__ __launch_bounds__(256) void gemm_qkv(
    const u16* __restrict__ A, const u16* __restrict__ Bw,
    const float* __restrict__ tct, const float* __restrict__ tst,
    const float* __restrict__ gain, float* __restrict__ projV,
    u16* __restrict__ Qn, u16* __restrict__ Kn) {
  __shared__ u16 As[128 * 64];
  __shared__ u16 Bs[128 * 64];
  const int tid = threadIdx.x;
  const int lane = tid & 63;
  const int wave = tid >> 6;
  const int ntile = PROJN >> 7;  // 24
  const int m0 = (blockIdx.x / ntile) << 7;
  const int n0 = (blockIdx.x % ntile) << 7;
  const int wr = (wave >> 1) << 6;
  const int wc = (wave & 1) << 6;
  const int ql = lane & 15;
  const int g = lane >> 4;
  const int K = 2048;

  const f32x4 zero4 = {0.f, 0.f, 0.f, 0.f};
  f32x4 acc[4][4];
#pragma unroll
  for (int m = 0; m < 4; m++)
#pragma unroll
    for (int n = 0; n < 4; n++) acc[m][n] = zero4;

  int srow[4], sslot[4];
#pragma unroll
  for (int i = 0; i < 4; i++) {
    int c = i * 256 + tid;
    srow[i] = c >> 3;
    sslot[i] = (c & 7) ^ (srow[i] & 7);
  }

  auto stage = [&](int kt) {
    const int k0 = kt << 6;
#pragma unroll
    for (int i = 0; i < 4; i++) {
      const u16* ga = A + (size_t)(m0 + srow[i]) * K + k0 + sslot[i] * 8;
      GLDS16(ga, As + (i * 256 + tid) * 8);
    }
#pragma unroll
    for (int i = 0; i < 4; i++) {
      const u16* gb = Bw + (size_t)(n0 + srow[i]) * K + k0 + sslot[i] * 8;
      GLDS16(gb, Bs + (i * 256 + tid) * 8);
    }
  };

  stage(0);
  for (int kt = 0;; kt++) {
    __syncthreads();
#pragma unroll
    for (int ks = 0; ks < 2; ks++) {
      const int sd = ks * 4 + g;
      short8 a[4], b[4];
#pragma unroll
      for (int m = 0; m < 4; m++) {
        int r = wr + m * 16 + ql;
        a[m] = *reinterpret_cast<const short8*>(As + r * 64 + ((sd ^ (r & 7)) << 3));
      }
#pragma unroll
      for (int n = 0; n < 4; n++) {
        int r = wc + n * 16 + ql;
        b[n] = *reinterpret_cast<const short8*>(Bs + r * 64 + ((sd ^ (r & 7)) << 3));
      }
#pragma unroll
      for (int m = 0; m < 4; m++)
#pragma unroll
        for (int n = 0; n < 4; n++)
          acc[m][n] = __builtin_amdgcn_mfma_f32_16x16x32_bf16(a[m], b[n], acc[m][n], 0, 0, 0);
    }
    if (kt + 1 == 32) break;
    __syncthreads();
    stage(kt + 1);
  }

  // ---- fused epilogue ----
  const int hslice = (n0 + wc) >> 6;     // 0..47
  const int browbase = m0 + wr + 4 * g;  // + 16m + r
  const int bb = (m0 + wr) >> 11;        // batch (tile never crosses b boundary)

  if (hslice >= 40) {
    // V: raw f32 to projV[(b*S+s)*512 + kvh*64 + d]
    float* dstV = projV + (size_t)browbase * 512 + (hslice - 40) * 64;
#pragma unroll
    for (int m = 0; m < 4; m++)
#pragma unroll
      for (int n = 0; n < 4; n++) {
        float* dp = dstV + (size_t)(16 * m) * 512 + n * 16 + ql;
#pragma unroll
        for (int r = 0; r < 4; r++) dp[(size_t)r * 512] = acc[m][n][r];
      }
    return;
  }

  // Q/K: rope + rmsnorm (+ gain*SCL2E prescale for Q)
  const bool isQ = (hslice < 32);
  // SCL2E = 0.125 * log2(e): folds attn scale+exp2-conversion into Q
  const float scale = isQ ? gain[0] * 0.18033688011112042f : 1.0f;
  u16* outp = isQ ? Qn + ((size_t)(bb * H_ + hslice)) * S_ * HD_
                  : Kn + ((size_t)(bb * KVH_ + (hslice - 32))) * S_ * HD_;
  const int jj0 = ql, jj1 = 16 + ql;

#pragma unroll
  for (int m = 0; m < 4; m++) {
    const int sb = (browbase + 16 * m) & (S_ - 1);
    float c0a[4], c1a[4], s0a[4], s1a[4];
    *reinterpret_cast<float4*>(c0a) = *reinterpret_cast<const float4*>(&tct[jj0 * 2048 + sb]);
    *reinterpret_cast<float4*>(c1a) = *reinterpret_cast<const float4*>(&tct[jj1 * 2048 + sb]);
    *reinterpret_cast<float4*>(s0a) = *reinterpret_cast<const float4*>(&tst[jj0 * 2048 + sb]);
    *reinterpret_cast<float4*>(s1a) = *reinterpret_cast<const float4*>(&tst[jj1 * 2048 + sb]);
    float o[4][4], iv[4];
#pragma unroll
    for (int r = 0; r < 4; r++) {
      const float a0 = acc[m][0][r], a1 = acc[m][1][r];
      const float a2 = acc[m][2][r], a3 = acc[m][3][r];
      const float l0 = a0 * c0a[r] - a2 * s0a[r];
      const float l1 = a1 * c1a[r] - a3 * s1a[r];
      const float h0 = a2 * c0a[r] + a0 * s0a[r];
      const float h1 = a3 * c1a[r] + a1 * s1a[r];
      o[0][r] = l0; o[1][r] = l1; o[2][r] = h0; o[3][r] = h1;
      float sr = (l0 * l0 + l1 * l1) + (h0 * h0 + h1 * h1);
      sr += __shfl_xor(sr, 1);
      sr += __shfl_xor(sr, 2);
      sr += __shfl_xor(sr, 4);
      sr += __shfl_xor(sr, 8);
      iv[r] = rsqrtf(sr * (1.0f / 64.0f) + 1e-6f) * scale;
    }
#pragma unroll
    for (int n = 0; n < 4; n++) {
      const int d = n * 16 + ql;
#pragma unroll
      for (int r = 0; r < 4; r++)
        outp[(size_t)(sb + r) * HD_ + d] = f2bf(o[n][r] * iv[r]);
    }
  }
}

// ---------------- V: transpose to (B,KVH,HD,S) bf16 + V_flat f32 output ----------------
__global__ __launch_bounds__(256) void vtrans(const float* __restrict__ projV,
                                              u16* __restrict__ Vt,
                                              float* __restrict__ Vout) {
  __shared__ float tile[64][65];
  const int bid = blockIdx.x;  // B_*KVH_*(S_/64)
  const int st = bid & 31;
  const int s0 = st << 6;
  const int kvh = (bid >> 5) & 7;
  const int b = bid >> 8;
  const int t = threadIdx.x;
  const int sr = t >> 2;
  const int d0 = (t & 3) << 4;
  const float* src = projV + ((size_t)(b * S_ + s0 + sr)) * 512 + kvh * 64 + d0;
  float v[16];
#pragma unroll
  for (int i = 0; i < 16; i += 4) {
    float4 x = *reinterpret_cast<const float4*>(src + i);
    v[i] = x.x; v[i + 1] = x.y; v[i + 2] = x.z; v[i + 3] = x.w;
  }
#pragma unroll
  for (int hh = 0; hh < 4; hh++) {
    int hq = kvh * 4 + hh;
    float* dst = Vout + (((size_t)(hq * B_ + b)) * S_ + s0 + sr) * HD_ + d0;
#pragma unroll
    for (int i = 0; i < 16; i += 4)
      *reinterpret_cast<float4*>(dst + i) = make_float4(v[i], v[i + 1], v[i + 2], v[i + 3]);
  }
#pragma unroll
  for (int i = 0; i < 16; i++) tile[sr][d0 + i] = v[i];
  __syncthreads();
  const int d = t >> 2;
  const int sc = (t & 3) << 4;
  union { short8 v8; u16 u[8]; } o0, o1;
#pragma unroll
  for (int i = 0; i < 8; i++) o0.u[i] = f2bf(tile[sc + i][d]);
#pragma unroll
  for (int i = 0; i < 8; i++) o1.u[i] = f2bf(tile[sc + 8 + i][d]);
  u16* dst = Vt + (((size_t)(b * KVH_ + kvh)) * HD_ + d) * S_ + s0 + sc;
  *reinterpret_cast<short8*>(dst) = o0.v8;
  *reinterpret_cast<short8*>(dst + 8) = o1.v8;
}

// ---------------- flash attention (causal, GQA) ----------------
// R12: Q prescaled by gain*SCL2E in gemm_qkv => pv = exp2f(sc) directly
// (the -12 bias cancels in softmax ratio; max exp2 arg 11.54 -> <=2980, safe).
// Structure as R11: 1024 blocks LPT, 40KB LDS, launch_bounds(256,2).
__global__ __launch_bounds__(256, 2) void attn_fwd(const u16* __restrict__ Qn,
                                                   const u16* __restrict__ Kn,
                                                   const u16* __restrict__ Vt,
                                                   u16* __restrict__ Aout) {
  __shared__ u16 Ks[2][64 * 64];
  __shared__ u16 Vs[2][64 * 64];
  __shared__ u16 Ps[4][1024];
  const int bid = blockIdx.x;  // 64 tile-slots x 16 groups
  const int grp = bid & 15;
  const int i = bid >> 4;
  const int qt = 63 - i;  // LPT: longest first
  const int b = grp >> 3;
  const int kvh = grp & 7;
  const int q0 = qt << 5;
  const int JT = (qt >> 1) + 1;
  const int tid = threadIdx.x;
  const int lane = tid & 63;
  const int wave = tid >> 6;
  const int h = kvh * 4 + wave;
  const int ql = lane & 15;
  const int g = lane >> 4;

  short8 qa[2][2];
  int rowq[2];
#pragma unroll
  for (int f = 0; f < 2; f++) {
    rowq[f] = q0 + 16 * f + ql;
    const u16* qb = Qn + (((size_t)(b * H_ + h)) * S_ + rowq[f]) * HD_;
    qa[f][0] = *reinterpret_cast<const short8*>(qb + g * 8);
    qa[f][1] = *reinterpret_cast<const short8*>(qb + 32 + g * 8);
  }

  const f32x4 zero4 = {0.f, 0.f, 0.f, 0.f};
  f32x4 oacc[4][2];
#pragma unroll
  for (int dn = 0; dn < 4; dn++)
#pragma unroll
    for (int f = 0; f < 2; f++) oacc[dn][f] = zero4;
  float psum[2] = {0.f, 0.f};

  const u16* kg = Kn + ((size_t)(b * KVH_ + kvh)) * S_ * HD_;
  const u16* vg = Vt + ((size_t)(b * KVH_ + kvh)) * HD_ * S_;

  const int c0 = tid, c1 = 256 + tid;
  const int r0 = c0 >> 3, sl0 = (c0 & 7) ^ (r0 & 7);
  const int r1 = c1 >> 3, sl1 = (c1 & 7) ^ (r1 & 7);
  const int xsw2 = (ql & 7) << 2;

  auto stage = [&](int jt, int buf) {
    const int j0 = jt << 6;
    GLDS16(kg + (size_t)(j0 + r0) * HD_ + sl0 * 8, Ks[buf] + c0 * 8);
    GLDS16(kg + (size_t)(j0 + r1) * HD_ + sl1 * 8, Ks[buf] + c1 * 8);
    GLDS16(vg + (size_t)r0 * S_ + j0 + sl0 * 8, Vs[buf] + c0 * 8);
    GLDS16(vg + (size_t)r1 * S_ + j0 + sl1 * 8, Vs[buf] + c1 * 8);
  };

  stage(0, 0);
  __syncthreads();
  int cur = 0;
  for (int jt = 0; jt < JT; jt++) {
    if (jt + 1 < JT) stage(jt + 1, cur ^ 1);
    const int j0 = jt << 6;
    const u16* ksb = Ks[cur];
    const u16* vsb = Vs[cur];
    const bool diag = (jt == JT - 1);

    f32x4 sc[4][2];
#pragma unroll
    for (int n = 0; n < 4; n++)
#pragma unroll
      for (int f = 0; f < 2; f++) sc[n][f] = zero4;
    __builtin_amdgcn_s_setprio(1);
#pragma unroll
    for (int ks = 0; ks < 2; ks++) {
      const int sd = ks * 4 + g;
#pragma unroll
      for (int n = 0; n < 4; n++) {
        const int r = n * 16 + ql;
        short8 kf = *reinterpret_cast<const short8*>(ksb + r * 64 + ((sd ^ (r & 7)) << 3));
        sc[n][0] = __builtin_amdgcn_mfma_f32_16x16x32_bf16(kf, qa[0][ks], sc[n][0], 0, 0, 0);
        sc[n][1] = __builtin_amdgcn_mfma_f32_16x16x32_bf16(kf, qa[1][ks], sc[n][1], 0, 0, 0);
      }
    }
    __builtin_amdgcn_s_setprio(0);

    short8 pa[2][2];
#pragma unroll
    for (int f = 0; f < 2; f++) {
      float pv[4][4];
#pragma unroll
      for (int n = 0; n < 4; n++)
#pragma unroll
        for (int r = 0; r < 4; r++)
          pv[n][r] = exp2f(sc[n][f][r]);  // Q prescaled; bias cancels in ratio
      if (diag) {
#pragma unroll
        for (int n = 0; n < 4; n++)
#pragma unroll
          for (int r = 0; r < 4; r++)
            if ((j0 + n * 16 + 4 * g + r) > rowq[f]) pv[n][r] = 0.f;
      }
      u32* pw32 = reinterpret_cast<u32*>(Ps[wave]);
#pragma unroll
      for (int n = 0; n < 4; n++) {
        psum[f] += (pv[n][0] + pv[n][1]) + (pv[n][2] + pv[n][3]);
        union { u32 w; u16 hh[2]; } c01, c23;
        c01.hh[0] = f2bf(pv[n][0]); c01.hh[1] = f2bf(pv[n][1]);
        c23.hh[0] = f2bf(pv[n][2]); c23.hh[1] = f2bf(pv[n][3]);
        const int idx = ql * 32 + (((n << 3) + (g << 1)) ^ xsw2);
        pw32[idx] = c01.w;
        pw32[idx + 1] = c23.w;
      }
#pragma unroll
      for (int ks = 0; ks < 2; ks++)
        pa[f][ks] = *reinterpret_cast<const short8*>(
            Ps[wave] + ql * 64 + ((32 * ks + 8 * g) ^ (xsw2 << 1)));
    }

    __builtin_amdgcn_s_setprio(1);
#pragma unroll
    for (int ks = 0; ks < 2; ks++) {
      const int sd = ks * 4 + g;
#pragma unroll
      for (int dn = 0; dn < 4; dn++) {
        const int vr = dn * 16 + ql;
        short8 vf = *reinterpret_cast<const short8*>(vsb + vr * 64 + ((sd ^ (vr & 7)) << 3));
        oacc[dn][0] = __builtin_amdgcn_mfma_f32_16x16x32_bf16(vf, pa[0][ks], oacc[dn][0], 0, 0, 0);
        oacc[dn][1] = __builtin_amdgcn_mfma_f32_16x16x32_bf16(vf, pa[1][ks], oacc[dn][1], 0, 0, 0);
      }
    }
    __builtin_amdgcn_s_setprio(0);

    __syncthreads();
    cur ^= 1;
  }

#pragma unroll
  for (int f = 0; f < 2; f++) {
    float s = psum[f];
    s += __shfl_xor(s, 16);
    s += __shfl_xor(s, 32);
    const float il = 1.0f / s;
#pragma unroll
    for (int dn = 0; dn < 4; dn++) {
      union { short4v v; u16 uu[4]; } o;
#pragma unroll
      for (int r = 0; r < 4; r++) o.uu[r] = f2bf(oacc[dn][f][r] * il);
      u16* dst = Aout + ((size_t)b * S_ + rowq[f]) * D_ + h * HD_ + dn * 16 + 4 * g;
      *reinterpret_cast<short4v*>(dst) = o.v;
    }
  }
}

// ---------------- launcher ----------------
extern "C" void kernel_launch(void* const* d_in, const int* in_sizes, int n_in,
                              void* d_out, int out_size, void* d_ws,
                              size_t ws_size, hipStream_t stream) {
  const float* x = (const float*)d_in[0];
  const float* wqkv = (const float*)d_in[1];
  const float* wout = (const float*)d_in[2];
  const float* gain = (const float*)d_in[3];

  float* out_attn = (float*)d_out;                       // (B,S,D) f32
  float* out_vflat = out_attn + (size_t)B_ * S_ * D_;    // (H*B,S,HD) f32

  uint8_t* w = (uint8_t*)d_ws;
  u16* xb      = (u16*)(w);                     // 16,777,216 B
  u16* wqkvb   = (u16*)(w + 16777216);          // 12,582,912 B
  u16* woutb   = (u16*)(w + 29360128);          //  8,388,608 B
  float* projV = (float*)(w + 37748736);        //  8,388,608 B (V region only)
  u16* Qn      = (u16*)(w + 46137344);          // 16,777,216 B
  u16* Kn      = (u16*)(w + 62914560);          //  4,194,304 B
  u16* Vt      = (u16*)(w + 67108864);          //  4,194,304 B
  u16* attnb   = (u16*)(w + 71303168);          // 16,777,216 B
  float* tct   = (float*)(w + 88080384);        //    262,144 B
  float* tst   = (float*)(w + 88342528);        //    262,144 B
  // total: 88,604,672 B

  pack_bf16<<<4096, 256, 0, stream>>>(x, xb, B_ * S_ * D_);
  pack_bf16<<<3072, 256, 0, stream>>>(wqkv, wqkvb, PROJN * D_);
  pack_bf16<<<2048, 256, 0, stream>>>(wout, woutb, D_ * D_);
  rope_tabT<<<256, 256, 0, stream>>>(tct, tst);

  // fused: proj + rope + rmsnorm + prescale + pack (writes Qn, Kn, projV)
  gemm_qkv<<<(4096 / 128) * (3072 / 128), 256, 0, stream>>>(
      xb, wqkvb, tct, tst, gain, projV, Qn, Kn);
  vtrans<<<B_ * KVH_ * (S_ / 64), 256, 0, stream>>>(projV, Vt, out_vflat);
  attn_fwd<<<B_ * KVH_ * (S_ / 32), 256, 0, stream>>>(Qn, Kn, Vt, attnb);
  // attn_out = attn @ w_out^T : (4096 x 2048)
  gemm_bt<<<(4096 / 128) * (2048 / 128), 256, 0, stream>>>(attnb, woutb,
                                                           out_attn, 4096,
                                                           2048, 2048);
}